// Round 13
// baseline (572.661 us; speedup 1.0000x reference)
//
#include <hip/hip_runtime.h>
#include <stdint.h>

#define BATCH 4096
#define IN_DIM 1024
#define HID 16384
#define KACT 64
#define EPS2 0.08f   // margin; |bf16(v_mfma) - v_np| <= ~0.035 < EPS2/2 window proof (r7)
#define CCAP 128

typedef short bf16x8 __attribute__((ext_vector_type(8)));
typedef short short8 __attribute__((ext_vector_type(8)));
typedef unsigned short u16x4 __attribute__((ext_vector_type(4)));
typedef float f32x4 __attribute__((ext_vector_type(4)));

__device__ __forceinline__ uint16_t f2bf(float f) {
  uint32_t u = __float_as_uint(f);
  return (uint16_t)((u + 0x7FFFu + ((u >> 16) & 1u)) >> 16);
}
__device__ __forceinline__ float bf2f(uint16_t h) {
  return __uint_as_float((uint32_t)h << 16);
}
__device__ __forceinline__ uint32_t fmap(float f) {
  uint32_t u = __float_as_uint(f);
  return (u & 0x80000000u) ? ~u : (u | 0x80000000u);
}
__device__ __forceinline__ void gload_lds16(const void* g, void* l) {
  __builtin_amdgcn_global_load_lds(
      (const __attribute__((address_space(1))) unsigned int*)g,
      (__attribute__((address_space(3))) unsigned int*)l, 16, 0, 0);
}

// ---------------------------------------------------------------------------
// convert_both: bf16 cast of x -> A2 and Wenc -> B2 in one launch
// ---------------------------------------------------------------------------
__global__ __launch_bounds__(256) void convert_both(const float* __restrict__ x,
                                                    const float* __restrict__ Wenc,
                                                    uint16_t* __restrict__ A2,
                                                    uint16_t* __restrict__ B2) {
  const size_t nx4 = (size_t)BATCH * IN_DIM / 4;
  const size_t nw4 = (size_t)HID * IN_DIM / 4;
  for (size_t i = (size_t)blockIdx.x * 256 + threadIdx.x; i < nx4;
       i += (size_t)gridDim.x * 256) {
    f32x4 v = *(const f32x4*)(x + i * 4);
    uint64_t pk = (uint64_t)f2bf(v[0]) | ((uint64_t)f2bf(v[1]) << 16) |
                  ((uint64_t)f2bf(v[2]) << 32) | ((uint64_t)f2bf(v[3]) << 48);
    *(uint64_t*)(A2 + i * 4) = pk;
  }
  for (size_t i = (size_t)blockIdx.x * 256 + threadIdx.x; i < nw4;
       i += (size_t)gridDim.x * 256) {
    f32x4 v = *(const f32x4*)(Wenc + i * 4);
    uint64_t pk = (uint64_t)f2bf(v[0]) | ((uint64_t)f2bf(v[1]) << 16) |
                  ((uint64_t)f2bf(v[2]) << 32) | ((uint64_t)f2bf(v[3]) << 48);
    *(uint64_t*)(B2 + i * 4) = pk;
  }
}

// ---------------------------------------------------------------------------
// bf16 MFMA GEMM, 128x128 tile, BK=64, K=1024, XCD-grouped order, 2-phase dbuf.
// C (bf16) stored into the UPPER 32KB half of each 64KB f32 output row
// (u16 offset +HID). Blocks with bn<64 also stream ZEROS over their 128x128
// f32 patch of the LOWER half (cols 0..8191) — pre-zeroing for the scatter.
// ---------------------------------------------------------------------------
__global__ __launch_bounds__(256) void mfma_gemm(const uint16_t* __restrict__ A2,
                                                 const uint16_t* __restrict__ B2,
                                                 uint16_t* __restrict__ Cb) {
  __shared__ __attribute__((aligned(16))) char lds[2][32768];
  const int tid = threadIdx.x;
  const int lane = tid & 63;
  const int wave = tid >> 6;
  const int wr = wave >> 1, wc = wave & 1;

  const int bid = blockIdx.x;
  const int xcd = bid & 7;
  const int pos = bid >> 3;
  const int g = pos >> 4;
  const int rem = pos & 15;
  const int bm = xcd * 4 + (rem >> 2);
  const int bn = g * 4 + (rem & 3);

  const char* Abase = (const char*)(A2 + (size_t)(bm * 128) * IN_DIM);
  const char* Bbase = (const char*)(B2 + (size_t)(bn * 128) * IN_DIM);

  const int srow = lane >> 3;
  const int scolb = (lane & 7) << 4;

  auto stage = [&](int kt, int buf) {
    const int colB = kt * 128;
#pragma unroll
    for (int j = 0; j < 4; ++j) {
      const int r0 = wave * 32 + j * 8;
      const int row = r0 + srow;
      const int swz = (row & 7) << 4;
      gload_lds16(Abase + (size_t)row * 2048 + colB + (scolb ^ swz),
                  lds[buf] + r0 * 128);
      gload_lds16(Bbase + (size_t)row * 2048 + colB + (scolb ^ swz),
                  lds[buf] + 16384 + r0 * 128);
    }
  };

  f32x4 acc[4][4] = {};

  stage(0, 0);
  __syncthreads();

  for (int kt = 0; kt < 16; ++kt) {
    const int buf = kt & 1;
    if (kt < 15) stage(kt + 1, buf ^ 1);

#pragma unroll
    for (int ku = 0; ku < 2; ++ku) {
      bf16x8 af[4], bf_[4];
      const int kb = ku * 64 + ((lane >> 4) << 4);
#pragma unroll
      for (int m = 0; m < 4; ++m) {
        const int row = wr * 64 + m * 16 + (lane & 15);
        af[m] = *(const bf16x8*)(lds[buf] + row * 128 + (kb ^ ((row & 7) << 4)));
      }
#pragma unroll
      for (int n = 0; n < 4; ++n) {
        const int row = wc * 64 + n * 16 + (lane & 15);
        bf_[n] = *(const bf16x8*)(lds[buf] + 16384 + row * 128 +
                                  (kb ^ ((row & 7) << 4)));
      }
#pragma unroll
      for (int m = 0; m < 4; ++m)
#pragma unroll
        for (int n = 0; n < 4; ++n)
          acc[m][n] = __builtin_amdgcn_mfma_f32_16x16x32_bf16(bf_[n], af[m],
                                                              acc[m][n], 0, 0, 0);
    }
    __syncthreads();
  }

  // C store: bf16 into upper 32KB half of each 64KB f32 row (u16 offset +HID)
#pragma unroll
  for (int m = 0; m < 4; ++m) {
    const int grow = bm * 128 + wr * 64 + m * 16 + (lane & 15);
    uint16_t* rowp = Cb + (size_t)grow * (2 * HID) + HID;
#pragma unroll
    for (int n = 0; n < 4; ++n) {
      const int gcol0 = bn * 128 + wc * 64 + n * 16 + ((lane >> 4) << 2);
      uint2 pk;
      pk.x = (uint32_t)f2bf(acc[m][n][0]) | ((uint32_t)f2bf(acc[m][n][1]) << 16);
      pk.y = (uint32_t)f2bf(acc[m][n][2]) | ((uint32_t)f2bf(acc[m][n][3]) << 16);
      *(uint2*)(rowp + gcol0) = pk;
    }
  }

  // pre-zero: blocks with bn<64 zero their 128x128 f32 patch (lower half)
  if (bn < 64) {
    float* zbase = (float*)Cb;
    const int c0 = bn * 128 + (tid & 31) * 4;
    const f32x4 z = {0.f, 0.f, 0.f, 0.f};
    for (int r = tid >> 5; r < 128; r += 8)
      *(f32x4*)(zbase + (size_t)(bm * 128 + r) * HID + c0) = z;
  }
}

// ---------------------------------------------------------------------------
// select_decode: reads bf16 C (upper half of row), binary-search bracket,
// classify sure/window (no bitmap — keep == v > sure_thr), dense-write only
// the upper-half f32 (idx >= 8192), scatter sure winners with idx < 8192
// into the GEMM-pre-zeroed lower half, collect sure list, decode it.
// ---------------------------------------------------------------------------
__global__ __launch_bounds__(256) void select_decode(float* __restrict__ enc,
                                                     int* __restrict__ cand_idx,
                                                     float* __restrict__ cand_aval,
                                                     int* __restrict__ row_cnt,
                                                     int* __restrict__ row_need,
                                                     const uint16_t* __restrict__ WdT_b,
                                                     float* __restrict__ decoded) {
  const int b = blockIdx.x;
  const int tid = threadIdx.x;
  const int lane = tid & 63;
  const int wid = tid >> 6;
  float* rowf = enc + (size_t)b * HID;
  const uint16_t* rb = (const uint16_t*)rowf + HID;  // bf16 C in upper half

  float vals[64];
#pragma unroll
  for (int i = 0; i < 8; ++i) {
    short8 v8 = *(const short8*)(rb + tid * 8 + i * 2048);
#pragma unroll
    for (int j = 0; j < 8; ++j) vals[i * 8 + j] = bf2f((uint16_t)v8[j]);
  }

  // ---- binary search bracket: count(v > hi) < 64 <= count(v > lo) ----
  __shared__ uint32_t wsum[2][4];
  float lo = -16.0f, hi = 16.0f;
  for (int it = 0; it < 11; ++it) {
    const float mid = 0.5f * (lo + hi);
    uint32_t c = 0;
#pragma unroll
    for (int q = 0; q < 64; ++q) c += (vals[q] > mid);
#pragma unroll
    for (int d = 1; d < 64; d <<= 1) c += __shfl_xor(c, d, 64);
    if (lane == 0) wsum[it & 1][wid] = c;
    __syncthreads();
    const uint32_t tot =
        wsum[it & 1][0] + wsum[it & 1][1] + wsum[it & 1][2] + wsum[it & 1][3];
    if (tot >= (uint32_t)KACT) lo = mid; else hi = mid;
  }

  const float sure_thr = hi + EPS2;
  const float cand_lo = lo - EPS2;

  // ---- classify: emit window candidates; count sure ----
  __shared__ uint32_t s_nc;
  __shared__ uint32_t s_csw[4];
  __shared__ int sidx[KACT];
  __shared__ float sval[KACT];
  if (tid == 0) s_nc = 0u;
  __syncthreads();

  uint32_t cs = 0;
#pragma unroll
  for (int i = 0; i < 8; ++i)
#pragma unroll
    for (int j = 0; j < 8; ++j) {
      const float v = vals[i * 8 + j];
      const int idx = tid * 8 + i * 2048 + j;
      if (v > sure_thr) {
        ++cs;
      } else if (v >= cand_lo) {
        uint32_t p = atomicAdd(&s_nc, 1u);
        if (p < CCAP) {
          cand_idx[(size_t)b * CCAP + p] = idx;
          cand_aval[(size_t)b * CCAP + p] = v;
        }
      }
    }
#pragma unroll
  for (int d = 1; d < 64; d <<= 1) cs += __shfl_xor(cs, d, 64);
  if (lane == 0) s_csw[wid] = cs;
  __syncthreads();
  const int ns = (int)(s_csw[0] + s_csw[1] + s_csw[2] + s_csw[3]);  // <= 63
  if (tid == 0) {
    row_cnt[b] = (int)min(s_nc, (uint32_t)CCAP);
    row_need[b] = KACT - ns;   // >= 1 by bracket invariant
  }

  // ---- write pass: dense upper half (i>=4), scatter sure in lower half;
  //      collect sure (idx,val) list via prefix scan (thread-major order) ----
  uint64_t keepm = 0ull;
  uint32_t c2 = 0;
#pragma unroll
  for (int i = 0; i < 8; ++i) {
    f32x4 o0, o1;
#pragma unroll
    for (int j = 0; j < 8; ++j) {
      const int idx = tid * 8 + i * 2048 + j;
      const float v = vals[i * 8 + j];
      const bool keep = v > sure_thr;
      const float ov = keep ? v : 0.0f;
      if (j < 4) o0[j] = ov; else o1[j - 4] = ov;
      if (keep) {
        keepm |= (1ull << (i * 8 + j));
        ++c2;
        if (i < 4) rowf[idx] = v;   // scatter into pre-zeroed lower half
      }
    }
    if (i >= 4) {                    // dense write: upper half only
      *(f32x4*)(rowf + tid * 8 + i * 2048) = o0;
      *(f32x4*)(rowf + tid * 8 + i * 2048 + 4) = o1;
    }
  }
  __shared__ uint32_t psum[4];
  uint32_t p = c2;
#pragma unroll
  for (int d = 1; d < 64; d <<= 1) {
    uint32_t o = __shfl_up(p, d, 64);
    if (lane >= d) p += o;
  }
  if (lane == 63) psum[wid] = p;
  __syncthreads();
  uint32_t off = 0;
  for (int w = 0; w < wid; ++w) off += psum[w];
  uint32_t posn = off + p - c2;
#pragma unroll
  for (int i = 0; i < 8; ++i)
#pragma unroll
    for (int j = 0; j < 8; ++j) {
      if ((keepm >> (i * 8 + j)) & 1ull) {
        if (posn < KACT) {
          sidx[posn] = tid * 8 + i * 2048 + j;
          sval[posn] = vals[i * 8 + j];
        }
        ++posn;
      }
    }
  __syncthreads();

  // ---- decode sure entries: decoded[b,:] = sum_k sval[k]*WdT[sidx[k],:] ----
  f32x4 acc = {0.f, 0.f, 0.f, 0.f};
#pragma unroll 4
  for (int k = 0; k < ns; ++k) {
    const u16x4 w4 = *(const u16x4*)(WdT_b + (size_t)sidx[k] * IN_DIM + tid * 4);
    const float v = sval[k];
    acc[0] = fmaf(v, bf2f(w4[0]), acc[0]);
    acc[1] = fmaf(v, bf2f(w4[1]), acc[1]);
    acc[2] = fmaf(v, bf2f(w4[2]), acc[2]);
    acc[3] = fmaf(v, bf2f(w4[3]), acc[3]);
  }
  *(f32x4*)(decoded + (size_t)b * IN_DIM + tid * 4) = acc;
}

// ---------------------------------------------------------------------------
// exact_patch: 192 threads; thread (c=t&63, p=t>>6) computes panel p of
// candidate c (sequential k-ascending fp32 chain, Kc=384 breaks — r3-proven
// np scheme); rank (val desc, idx asc); winners patch sparse row AND add
// their contribution to decoded[b,:].
// ---------------------------------------------------------------------------
__global__ __launch_bounds__(192) void exact_patch(const float* __restrict__ x,
                                                   const float* __restrict__ Wenc,
                                                   const int* __restrict__ cand_idx,
                                                   const float* __restrict__ cand_aval,
                                                   const int* __restrict__ row_cnt,
                                                   const int* __restrict__ row_need,
                                                   float* __restrict__ enc,
                                                   const uint16_t* __restrict__ WdT_b,
                                                   float* __restrict__ decoded) {
  const int b = blockIdx.x;
  const int t = threadIdx.x;
  __shared__ float xs[IN_DIM];
  for (int i = t; i < IN_DIM / 4; i += 192)
    *(f32x4*)(xs + i * 4) = *(const f32x4*)(x + (size_t)b * IN_DIM + i * 4);

  const int cnt = row_cnt[b];
  const int need = row_need[b];
  __shared__ int eidx[CCAP];
  __shared__ float eaval[CCAP];
  __shared__ float spp[CCAP][3];
  __shared__ float evals[CCAP];
  __shared__ int widx[KACT];
  __shared__ float wval[KACT];
  for (int c = t; c < cnt; c += 192) {
    eidx[c] = cand_idx[(size_t)b * CCAP + c];
    eaval[c] = cand_aval[(size_t)b * CCAP + c];
  }
  __syncthreads();

  const int p = t >> 6;            // panel 0..2
  const int lane = t & 63;
  const int k0 = p * 384;
  const int k1 = (p == 2) ? 1024 : (k0 + 384);

  for (int c = lane; c < cnt; c += 64) {
    const float* w = Wenc + (size_t)eidx[c] * IN_DIM;
    float acc = 0.f;
    for (int k = k0; k < k1; k += 16) {
      const f32x4 w0 = *(const f32x4*)(w + k);
      const f32x4 w1 = *(const f32x4*)(w + k + 4);
      const f32x4 w2 = *(const f32x4*)(w + k + 8);
      const f32x4 w3 = *(const f32x4*)(w + k + 12);
#pragma unroll
      for (int j = 0; j < 4; ++j) acc = fmaf(xs[k + j], w0[j], acc);
#pragma unroll
      for (int j = 0; j < 4; ++j) acc = fmaf(xs[k + 4 + j], w1[j], acc);
#pragma unroll
      for (int j = 0; j < 4; ++j) acc = fmaf(xs[k + 8 + j], w2[j], acc);
#pragma unroll
      for (int j = 0; j < 4; ++j) acc = fmaf(xs[k + 12 + j], w3[j], acc);
    }
    spp[c][p] = acc;
  }
  __syncthreads();
  if (t < cnt) evals[t] = (spp[t][0] + spp[t][1]) + spp[t][2];
  __syncthreads();

  if (t < cnt && need > 0) {
    const float e = evals[t];
    const int myidx = eidx[t];
    int rank = 0;
    for (int c = 0; c < cnt; ++c)
      rank += (evals[c] > e) || (evals[c] == e && eidx[c] < myidx);
    if (rank < need) {
      const float v = eaval[t];
      enc[(size_t)b * HID + myidx] = v;   // patch sparse row
      widx[rank] = myidx;                  // rank in [0,need) unique
      wval[rank] = v;
    }
  }
  __syncthreads();

  const int nw = (need > 0) ? min(need, cnt) : 0;
  for (int wi = 0; wi < nw; ++wi) {
    const float v = wval[wi];
    const uint16_t* wrow = WdT_b + (size_t)widx[wi] * IN_DIM;
    for (int s = t; s < IN_DIM / 4; s += 192) {
      f32x4 d = *(f32x4*)(decoded + (size_t)b * IN_DIM + s * 4);
      const u16x4 w4 = *(const u16x4*)(wrow + s * 4);
      d[0] = fmaf(v, bf2f(w4[0]), d[0]);
      d[1] = fmaf(v, bf2f(w4[1]), d[1]);
      d[2] = fmaf(v, bf2f(w4[2]), d[2]);
      d[3] = fmaf(v, bf2f(w4[3]), d[3]);
      *(f32x4*)(decoded + (size_t)b * IN_DIM + s * 4) = d;
    }
    __syncthreads();
  }
}

// ---------------------------------------------------------------------------
// W_dec [IN_DIM][HID] f32 -> W_decT [HID][IN_DIM] bf16
// ---------------------------------------------------------------------------
__global__ __launch_bounds__(256) void transpose_wdec(const float* __restrict__ Wd,
                                                      uint16_t* __restrict__ WdT_b) {
  __shared__ float t[32][33];
  const int tx = threadIdx.x & 31;
  const int ty = threadIdx.x >> 5;
  const int hb = blockIdx.x * 32;
  const int ib = blockIdx.y * 32;
#pragma unroll
  for (int r = ty; r < 32; r += 8)
    t[r][tx] = Wd[(size_t)(ib + r) * HID + hb + tx];
  __syncthreads();
  const int tx2 = threadIdx.x & 15;
  const int ty2 = threadIdx.x >> 4;
#pragma unroll
  for (int c = ty2; c < 32; c += 16) {
    uint32_t pk = (uint32_t)f2bf(t[2 * tx2][c]) |
                  ((uint32_t)f2bf(t[2 * tx2 + 1][c]) << 16);
    *(uint32_t*)(WdT_b + (size_t)(hb + c) * IN_DIM + ib + 2 * tx2) = pk;
  }
}

// ---------------------------------------------------------------------------
// Fallback (r3-proven): fp32 vector GEMM + radix topk + gather decoder
// ---------------------------------------------------------------------------
__global__ __launch_bounds__(256) void enc_gemm(const float* __restrict__ A,
                                                const float* __restrict__ Bw,
                                                float* __restrict__ C) {
  __shared__ float As[16][132];
  __shared__ float Bs[16][132];
  const int tid = threadIdx.x;
  const int bm = blockIdx.y;
  const int bn = blockIdx.x;
  const int m0 = (tid >> 4) << 3;
  const int n0 = (tid & 15) << 3;
  float tot[8][8] = {};
  float acc[8][8] = {};
  const float* Ablk = A + (size_t)bm * 128 * IN_DIM;
  const float* Bblk = Bw + (size_t)bn * 128 * IN_DIM;
  for (int k0 = 0; k0 < IN_DIM; k0 += 16) {
#pragma unroll
    for (int l = 0; l < 2; ++l) {
      int li = tid + l * 256;
      int row = li >> 2;
      int c4 = (li & 3) << 2;
      float4 va = *reinterpret_cast<const float4*>(Ablk + (size_t)row * IN_DIM + k0 + c4);
      As[c4 + 0][row] = va.x; As[c4 + 1][row] = va.y;
      As[c4 + 2][row] = va.z; As[c4 + 3][row] = va.w;
      float4 vb = *reinterpret_cast<const float4*>(Bblk + (size_t)row * IN_DIM + k0 + c4);
      Bs[c4 + 0][row] = vb.x; Bs[c4 + 1][row] = vb.y;
      Bs[c4 + 2][row] = vb.z; Bs[c4 + 3][row] = vb.w;
    }
    __syncthreads();
#pragma unroll
    for (int kk = 0; kk < 16; ++kk) {
      float a[8], b[8];
#pragma unroll
      for (int i = 0; i < 8; ++i) a[i] = As[kk][m0 + i];
#pragma unroll
      for (int j = 0; j < 8; ++j) b[j] = Bs[kk][n0 + j];
#pragma unroll
      for (int i = 0; i < 8; ++i)
#pragma unroll
        for (int j = 0; j < 8; ++j) acc[i][j] = fmaf(a[i], b[j], acc[i][j]);
    }
    __syncthreads();
    const int kend = k0 + 16;
    if (kend == 384 || kend == 768 || kend == IN_DIM) {
#pragma unroll
      for (int i = 0; i < 8; ++i)
#pragma unroll
        for (int j = 0; j < 8; ++j) { tot[i][j] += acc[i][j]; acc[i][j] = 0.0f; }
    }
  }
  float* Cblk = C + (size_t)(bm * 128) * HID + bn * 128;
#pragma unroll
  for (int i = 0; i < 8; ++i) {
    float4 v0 = make_float4(tot[i][0], tot[i][1], tot[i][2], tot[i][3]);
    float4 v1 = make_float4(tot[i][4], tot[i][5], tot[i][6], tot[i][7]);
    *reinterpret_cast<float4*>(Cblk + (size_t)(m0 + i) * HID + n0) = v0;
    *reinterpret_cast<float4*>(Cblk + (size_t)(m0 + i) * HID + n0 + 4) = v1;
  }
}

__global__ __launch_bounds__(256) void topk_kernel(float* __restrict__ enc,
                                                   int* __restrict__ tk_idx,
                                                   float* __restrict__ tk_val) {
  const int b = blockIdx.x;
  const int tid = threadIdx.x;
  float* row = enc + (size_t)b * HID;
  uint32_t keys[64];
#pragma unroll
  for (int i = 0; i < 64; ++i) keys[i] = fmap(row[tid + (i << 8)]);
  __shared__ uint32_t hist[256];
  __shared__ uint32_t sfx[256];
  __shared__ uint32_t s_prefix, s_krem;
  __shared__ int eqidx[256];
  __shared__ uint32_t eqcnt;
  if (tid == 0) { s_prefix = 0u; s_krem = KACT; }
  for (int pass = 0; pass < 4; ++pass) {
    const int shift = 24 - pass * 8;
    hist[tid] = 0;
    __syncthreads();
    const uint32_t pm = pass ? (0xFFFFFFFFu << (shift + 8)) : 0u;
    const uint32_t prefix = s_prefix;
#pragma unroll
    for (int i = 0; i < 64; ++i)
      if ((keys[i] & pm) == prefix) atomicAdd(&hist[(keys[i] >> shift) & 255], 1u);
    __syncthreads();
    sfx[tid] = hist[tid];
    __syncthreads();
    for (int d = 1; d < 256; d <<= 1) {
      uint32_t add = (tid + d < 256) ? sfx[tid + d] : 0u;
      __syncthreads();
      sfx[tid] += add;
      __syncthreads();
    }
    const uint32_t krem = s_krem;
    __syncthreads();
    const uint32_t above = sfx[tid] - hist[tid];
    if (above < krem && sfx[tid] >= krem) {
      s_prefix = prefix | ((uint32_t)tid << shift);
      s_krem = krem - above;
    }
    __syncthreads();
  }
  const uint32_t T = s_prefix;
  const uint32_t take_eq = s_krem;
  if (tid == 0) eqcnt = 0;
  __syncthreads();
#pragma unroll
  for (int i = 0; i < 64; ++i)
    if (keys[i] == T) {
      uint32_t p = atomicAdd(&eqcnt, 1u);
      if (p < 256u) eqidx[p] = tid + (i << 8);
    }
  __syncthreads();
  if (tid == 0) {
    int n = (int)min(eqcnt, 256u);
    for (int a = 1; a < n; ++a) {
      int v = eqidx[a]; int c = a - 1;
      while (c >= 0 && eqidx[c] > v) { eqidx[c + 1] = eqidx[c]; --c; }
      eqidx[c + 1] = v;
    }
  }
  __syncthreads();
  uint64_t keepm = 0ull;
  uint32_t cnt = 0;
#pragma unroll
  for (int i = 0; i < 64; ++i) {
    const int idx = tid + (i << 8);
    const uint32_t u = keys[i];
    bool keep = (u > T);
    if (u == T) {
      for (uint32_t e = 0; e < take_eq; ++e)
        if (eqidx[e] == idx) { keep = true; break; }
    }
    if (keep) { keepm |= (1ull << i); ++cnt; }
  }
  sfx[tid] = cnt;
  __syncthreads();
  for (int d = 1; d < 256; d <<= 1) {
    uint32_t add = (tid >= d) ? sfx[tid - d] : 0u;
    __syncthreads();
    sfx[tid] += add;
    __syncthreads();
  }
  uint32_t pos = sfx[tid] - cnt;
#pragma unroll
  for (int i = 0; i < 64; ++i) {
    const int idx = tid + (i << 8);
    const uint32_t u = keys[i];
    const uint32_t sbits = (u & 0x80000000u) ? (u ^ 0x80000000u) : ~u;
    const float f = __uint_as_float(sbits);
    const bool keep = (keepm >> i) & 1ull;
    row[idx] = keep ? f : 0.0f;
    if (keep) {
      tk_idx[(size_t)b * KACT + pos] = idx;
      tk_val[(size_t)b * KACT + pos] = f;
      ++pos;
    }
  }
}

__global__ __launch_bounds__(256) void decoder_g(const int* __restrict__ tk_idx,
                                                 const float* __restrict__ tk_val,
                                                 const float* __restrict__ Wd,
                                                 float* __restrict__ out) {
  const int b = blockIdx.x;
  const int tid = threadIdx.x;
  __shared__ int sidx[KACT];
  __shared__ float sval[KACT];
  if (tid < KACT) {
    sidx[tid] = tk_idx[(size_t)b * KACT + tid];
    sval[tid] = tk_val[(size_t)b * KACT + tid];
  }
  __syncthreads();
  float acc[4] = {0.f, 0.f, 0.f, 0.f};
  for (int k = 0; k < KACT; ++k) {
    const int h = sidx[k];
    const float v = sval[k];
#pragma unroll
    for (int j = 0; j < 4; ++j)
      acc[j] = fmaf(v, Wd[(size_t)(tid + j * 256) * HID + h], acc[j]);
  }
#pragma unroll
  for (int j = 0; j < 4; ++j) out[(size_t)b * IN_DIM + tid + j * 256] = acc[j];
}

// ---------------------------------------------------------------------------
extern "C" void kernel_launch(void* const* d_in, const int* in_sizes, int n_in,
                              void* d_out, int out_size, void* d_ws, size_t ws_size,
                              hipStream_t stream) {
  const float* x = (const float*)d_in[0];
  const float* Wenc = (const float*)d_in[1];
  const float* Wdec = (const float*)d_in[2];
  float* out = (float*)d_out;
  float* decoded = out;
  float* sparse = out + (size_t)BATCH * IN_DIM;

  const size_t MB = 1024ull * 1024ull;
  char* ws = (char*)d_ws;
  int*   tk_idx    = (int*)(ws + 0 * MB);
  float* tk_val    = (float*)(ws + 1 * MB);
  int*   cand_idx  = (int*)(ws + 2 * MB);
  float* cand_aval = (float*)(ws + 4 * MB);
  int*   row_cnt   = (int*)(ws + 6 * MB);
  int*   row_need  = (int*)(ws + 6 * MB + 65536);
  uint16_t* A2     = (uint16_t*)(ws + 8 * MB);
  uint16_t* B2     = (uint16_t*)(ws + 16 * MB);
  uint16_t* WdT_b  = (uint16_t*)(ws + 48 * MB);

  const size_t need_new = 80 * MB;

  if (ws_size >= need_new) {
    convert_both<<<2048, 256, 0, stream>>>(x, Wenc, A2, B2);
    mfma_gemm<<<4096, 256, 0, stream>>>(A2, B2, (uint16_t*)sparse);
    transpose_wdec<<<dim3(HID / 32, IN_DIM / 32), 256, 0, stream>>>(Wdec, WdT_b);
    select_decode<<<BATCH, 256, 0, stream>>>(sparse, cand_idx, cand_aval,
                                             row_cnt, row_need, WdT_b, decoded);
    exact_patch<<<BATCH, 192, 0, stream>>>(x, Wenc, cand_idx, cand_aval,
                                           row_cnt, row_need, sparse,
                                           WdT_b, decoded);
  } else {
    enc_gemm<<<dim3(HID / 128, BATCH / 128), 256, 0, stream>>>(x, Wenc, sparse);
    topk_kernel<<<BATCH, 256, 0, stream>>>(sparse, tk_idx, tk_val);
    decoder_g<<<BATCH, 256, 0, stream>>>(tk_idx, tk_val, Wdec, decoded);
  }
}

// Round 14
// 554.784 us; speedup vs baseline: 1.0322x; 1.0322x over previous
//
#include <hip/hip_runtime.h>
#include <stdint.h>

#define BATCH 4096
#define IN_DIM 1024
#define HID 16384
#define KACT 64
#define EPS2 0.08f   // margin; |bf16(v_mfma) - v_np| <= ~0.035 < EPS2 window proof (r7)
#define CCAP 128

typedef short bf16x8 __attribute__((ext_vector_type(8)));
typedef short short8 __attribute__((ext_vector_type(8)));
typedef unsigned short u16x4 __attribute__((ext_vector_type(4)));
typedef float f32x4 __attribute__((ext_vector_type(4)));

__device__ __forceinline__ uint16_t f2bf(float f) {
  uint32_t u = __float_as_uint(f);
  return (uint16_t)((u + 0x7FFFu + ((u >> 16) & 1u)) >> 16);
}
__device__ __forceinline__ float bf2f(uint16_t h) {
  return __uint_as_float((uint32_t)h << 16);
}
__device__ __forceinline__ uint32_t fmap(float f) {
  uint32_t u = __float_as_uint(f);
  return (u & 0x80000000u) ? ~u : (u | 0x80000000u);
}
__device__ __forceinline__ void gload_lds16(const void* g, void* l) {
  __builtin_amdgcn_global_load_lds(
      (const __attribute__((address_space(1))) unsigned int*)g,
      (__attribute__((address_space(3))) unsigned int*)l, 16, 0, 0);
}

// ---------------------------------------------------------------------------
// Plain bf16 cast: out[i] = bf16(in[i]), 4 elems/thread
// ---------------------------------------------------------------------------
__global__ __launch_bounds__(256) void convert_bf16(const float* __restrict__ in,
                                                    uint16_t* __restrict__ out,
                                                    size_t n4) {
  for (size_t i = (size_t)blockIdx.x * 256 + threadIdx.x; i < n4;
       i += (size_t)gridDim.x * 256) {
    f32x4 v = *(const f32x4*)(in + i * 4);
    uint64_t pk = (uint64_t)f2bf(v[0]) | ((uint64_t)f2bf(v[1]) << 16) |
                  ((uint64_t)f2bf(v[2]) << 32) | ((uint64_t)f2bf(v[3]) << 48);
    *(uint64_t*)(out + i * 4) = pk;
  }
}

// ---------------------------------------------------------------------------
// bf16 MFMA GEMM, 128x128 tile, BK=64, K=1024, XCD-grouped order.
// 2-phase double-buffered LDS; swapped MFMA operands -> packed 8B bf16 stores
// (NON-TEMPORAL: C is written once, read once by select — no reuse).
// ---------------------------------------------------------------------------
__global__ __launch_bounds__(256) void mfma_gemm(const uint16_t* __restrict__ A2,
                                                 const uint16_t* __restrict__ B2,
                                                 uint16_t* __restrict__ Cb) {
  __shared__ __attribute__((aligned(16))) char lds[2][32768];
  const int tid = threadIdx.x;
  const int lane = tid & 63;
  const int wave = tid >> 6;
  const int wr = wave >> 1, wc = wave & 1;

  const int bid = blockIdx.x;
  const int xcd = bid & 7;
  const int pos = bid >> 3;
  const int g = pos >> 4;
  const int rem = pos & 15;
  const int bm = xcd * 4 + (rem >> 2);
  const int bn = g * 4 + (rem & 3);

  const char* Abase = (const char*)(A2 + (size_t)(bm * 128) * IN_DIM);
  const char* Bbase = (const char*)(B2 + (size_t)(bn * 128) * IN_DIM);

  const int srow = lane >> 3;
  const int scolb = (lane & 7) << 4;

  auto stage = [&](int kt, int buf) {
    const int colB = kt * 128;
#pragma unroll
    for (int j = 0; j < 4; ++j) {
      const int r0 = wave * 32 + j * 8;
      const int row = r0 + srow;
      const int swz = (row & 7) << 4;
      gload_lds16(Abase + (size_t)row * 2048 + colB + (scolb ^ swz),
                  lds[buf] + r0 * 128);
      gload_lds16(Bbase + (size_t)row * 2048 + colB + (scolb ^ swz),
                  lds[buf] + 16384 + r0 * 128);
    }
  };

  f32x4 acc[4][4] = {};

  stage(0, 0);
  __syncthreads();

  for (int kt = 0; kt < 16; ++kt) {
    const int buf = kt & 1;
    if (kt < 15) stage(kt + 1, buf ^ 1);

#pragma unroll
    for (int ku = 0; ku < 2; ++ku) {
      bf16x8 af[4], bf_[4];
      const int kb = ku * 64 + ((lane >> 4) << 4);
#pragma unroll
      for (int m = 0; m < 4; ++m) {
        const int row = wr * 64 + m * 16 + (lane & 15);
        af[m] = *(const bf16x8*)(lds[buf] + row * 128 + (kb ^ ((row & 7) << 4)));
      }
#pragma unroll
      for (int n = 0; n < 4; ++n) {
        const int row = wc * 64 + n * 16 + (lane & 15);
        bf_[n] = *(const bf16x8*)(lds[buf] + 16384 + row * 128 +
                                  (kb ^ ((row & 7) << 4)));
      }
#pragma unroll
      for (int m = 0; m < 4; ++m)
#pragma unroll
        for (int n = 0; n < 4; ++n)
          acc[m][n] = __builtin_amdgcn_mfma_f32_16x16x32_bf16(bf_[n], af[m],
                                                              acc[m][n], 0, 0, 0);
    }
    __syncthreads();
  }

#pragma unroll
  for (int m = 0; m < 4; ++m) {
    const int grow = bm * 128 + wr * 64 + m * 16 + (lane & 15);
    uint16_t* rowp = Cb + (size_t)grow * (2 * HID);
#pragma unroll
    for (int n = 0; n < 4; ++n) {
      const int gcol0 = bn * 128 + wc * 64 + n * 16 + ((lane >> 4) << 2);
      const uint64_t pk =
          (uint64_t)((uint32_t)f2bf(acc[m][n][0]) |
                     ((uint32_t)f2bf(acc[m][n][1]) << 16)) |
          ((uint64_t)((uint32_t)f2bf(acc[m][n][2]) |
                      ((uint32_t)f2bf(acc[m][n][3]) << 16)) << 32);
      __builtin_nontemporal_store(pk, (uint64_t*)(rowp + gcol0));
    }
  }
}

// ---------------------------------------------------------------------------
// select_bin: reads bf16 C (non-temporal: read-once), binary-search threshold
// bracket (11 iters), classifies sure/window, writes full f32 sparse row
// (NON-TEMPORAL: streaming, avoids L2 write-allocate HBM fetch), emits compact
// sure list + window candidates + per-row meta.
// ---------------------------------------------------------------------------
__global__ __launch_bounds__(256) void select_bin(float* __restrict__ enc,
                                                  int* __restrict__ tk_idx,
                                                  float* __restrict__ tk_val,
                                                  int* __restrict__ cand_idx,
                                                  float* __restrict__ cand_aval,
                                                  int* __restrict__ row_cnt,
                                                  int* __restrict__ row_need) {
  const int b = blockIdx.x;
  const int tid = threadIdx.x;
  const int lane = tid & 63;
  const int wid = tid >> 6;
  float* rowf = enc + (size_t)b * HID;
  const uint16_t* rb = (const uint16_t*)rowf;

  float vals[64];
#pragma unroll
  for (int i = 0; i < 8; ++i) {
    short8 v8 = __builtin_nontemporal_load(
        (const short8*)(rb + tid * 8 + i * 2048));
#pragma unroll
    for (int j = 0; j < 8; ++j) vals[i * 8 + j] = bf2f((uint16_t)v8[j]);
  }

  __shared__ uint32_t wsum[2][4];
  float lo = -16.0f, hi = 16.0f;
  for (int it = 0; it < 11; ++it) {
    const float mid = 0.5f * (lo + hi);
    uint32_t c = 0;
#pragma unroll
    for (int q = 0; q < 64; ++q) c += (vals[q] > mid);
#pragma unroll
    for (int d = 1; d < 64; d <<= 1) c += __shfl_xor(c, d, 64);
    if (lane == 0) wsum[it & 1][wid] = c;
    __syncthreads();
    const uint32_t tot =
        wsum[it & 1][0] + wsum[it & 1][1] + wsum[it & 1][2] + wsum[it & 1][3];
    if (tot >= (uint32_t)KACT) lo = mid; else hi = mid;
  }

  const float sure_thr = hi + EPS2;
  const float cand_lo = lo - EPS2;

  __shared__ uint32_t bitmap[HID / 32];
  __shared__ uint32_t s_nc, s_cs;
  bitmap[tid] = 0u;
  bitmap[tid + 256] = 0u;
  if (tid == 0) { s_nc = 0u; s_cs = 0u; }
  __syncthreads();

  uint32_t cs = 0;
#pragma unroll
  for (int i = 0; i < 8; ++i)
#pragma unroll
    for (int j = 0; j < 8; ++j) {
      const float v = vals[i * 8 + j];
      const int idx = tid * 8 + i * 2048 + j;
      if (v > sure_thr) {
        ++cs;
        atomicOr(&bitmap[idx >> 5], 1u << (idx & 31));
      } else if (v >= cand_lo) {
        uint32_t p = atomicAdd(&s_nc, 1u);
        if (p < CCAP) {
          cand_idx[(size_t)b * CCAP + p] = idx;
          cand_aval[(size_t)b * CCAP + p] = v;
        }
      }
    }
#pragma unroll
  for (int d = 1; d < 64; d <<= 1) cs += __shfl_xor(cs, d, 64);
  if (lane == 0) atomicAdd(&s_cs, cs);
  __syncthreads();

  if (tid == 0) {
    row_cnt[b] = (int)min(s_nc, (uint32_t)CCAP);
    row_need[b] = KACT - (int)s_cs;
  }

  uint64_t keepm = 0ull;
  uint32_t c2 = 0;
#pragma unroll
  for (int i = 0; i < 8; ++i) {
    f32x4 o0, o1;
#pragma unroll
    for (int j = 0; j < 8; ++j) {
      const int idx = tid * 8 + i * 2048 + j;
      const float v = vals[i * 8 + j];
      const bool keep = (bitmap[idx >> 5] >> (idx & 31)) & 1u;
      const float ov = keep ? v : 0.0f;
      if (j < 4) o0[j] = ov; else o1[j - 4] = ov;
      if (keep) { keepm |= (1ull << (i * 8 + j)); ++c2; }
    }
    __builtin_nontemporal_store(o0, (f32x4*)(rowf + tid * 8 + i * 2048));
    __builtin_nontemporal_store(o1, (f32x4*)(rowf + tid * 8 + i * 2048 + 4));
  }
  __shared__ uint32_t psum[4];
  uint32_t p = c2;
#pragma unroll
  for (int d = 1; d < 64; d <<= 1) {
    uint32_t o = __shfl_up(p, d, 64);
    if (lane >= d) p += o;
  }
  if (lane == 63) psum[wid] = p;
  __syncthreads();
  uint32_t off = 0;
  for (int w = 0; w < wid; ++w) off += psum[w];
  uint32_t posn = off + p - c2;
#pragma unroll
  for (int i = 0; i < 8; ++i)
#pragma unroll
    for (int j = 0; j < 8; ++j) {
      if ((keepm >> (i * 8 + j)) & 1ull) {
        if (posn < KACT) {
          tk_idx[(size_t)b * KACT + posn] = tid * 8 + i * 2048 + j;
          tk_val[(size_t)b * KACT + posn] = vals[i * 8 + j];
        }
        ++posn;
      }
    }
}

// ---------------------------------------------------------------------------
// exact_patch: 192 threads = 3 waves; thread (c = t&63, p = t>>6) computes
// panel p of candidate c (sequential k-ascending fp32 chain, Kc=384 breaks —
// r3-proven np scheme); rank (val desc, idx asc); winners patch sparse row
// and fill tk slots [KACT-need, KACT).
// ---------------------------------------------------------------------------
__global__ __launch_bounds__(192) void exact_patch(const float* __restrict__ x,
                                                   const float* __restrict__ Wenc,
                                                   const int* __restrict__ cand_idx,
                                                   const float* __restrict__ cand_aval,
                                                   const int* __restrict__ row_cnt,
                                                   const int* __restrict__ row_need,
                                                   float* __restrict__ enc,
                                                   int* __restrict__ tk_idx,
                                                   float* __restrict__ tk_val) {
  const int b = blockIdx.x;
  const int t = threadIdx.x;
  __shared__ float xs[IN_DIM];
  for (int i = t; i < IN_DIM / 4; i += 192)
    *(f32x4*)(xs + i * 4) = *(const f32x4*)(x + (size_t)b * IN_DIM + i * 4);

  const int cnt = row_cnt[b];
  const int need = row_need[b];
  __shared__ int eidx[CCAP];
  __shared__ float eaval[CCAP];
  __shared__ float spp[CCAP][3];
  __shared__ float evals[CCAP];
  for (int c = t; c < cnt; c += 192) {
    eidx[c] = cand_idx[(size_t)b * CCAP + c];
    eaval[c] = cand_aval[(size_t)b * CCAP + c];
  }
  __syncthreads();

  const int p = t >> 6;            // panel 0..2
  const int lane = t & 63;
  const int k0 = p * 384;
  const int k1 = (p == 2) ? 1024 : (k0 + 384);

  for (int c = lane; c < cnt; c += 64) {
    const float* w = Wenc + (size_t)eidx[c] * IN_DIM;
    float acc = 0.f;
    for (int k = k0; k < k1; k += 16) {
      const f32x4 w0 = *(const f32x4*)(w + k);
      const f32x4 w1 = *(const f32x4*)(w + k + 4);
      const f32x4 w2 = *(const f32x4*)(w + k + 8);
      const f32x4 w3 = *(const f32x4*)(w + k + 12);
#pragma unroll
      for (int j = 0; j < 4; ++j) acc = fmaf(xs[k + j], w0[j], acc);
#pragma unroll
      for (int j = 0; j < 4; ++j) acc = fmaf(xs[k + 4 + j], w1[j], acc);
#pragma unroll
      for (int j = 0; j < 4; ++j) acc = fmaf(xs[k + 8 + j], w2[j], acc);
#pragma unroll
      for (int j = 0; j < 4; ++j) acc = fmaf(xs[k + 12 + j], w3[j], acc);
    }
    spp[c][p] = acc;
  }
  __syncthreads();
  if (t < cnt) evals[t] = (spp[t][0] + spp[t][1]) + spp[t][2];
  __syncthreads();

  if (t < cnt && need > 0) {
    const float e = evals[t];
    const int myidx = eidx[t];
    int rank = 0;
    for (int c = 0; c < cnt; ++c)
      rank += (evals[c] > e) || (evals[c] == e && eidx[c] < myidx);
    if (rank < need) {
      const float v = eaval[t];
      enc[(size_t)b * HID + myidx] = v;
      const int slot = (KACT - need) + rank;
      tk_idx[(size_t)b * KACT + slot] = myidx;
      tk_val[(size_t)b * KACT + slot] = v;
    }
  }
}

// ---------------------------------------------------------------------------
// decoder_t: decoded[b,:] = sum_k val_k * WdT_b[idx_k,:] (bf16 weights)
// ---------------------------------------------------------------------------
__global__ __launch_bounds__(256) void decoder_t(const int* __restrict__ tk_idx,
                                                 const float* __restrict__ tk_val,
                                                 const uint16_t* __restrict__ WdT_b,
                                                 float* __restrict__ out) {
  const int b = blockIdx.x;
  const int tid = threadIdx.x;
  __shared__ int sidx[KACT];
  __shared__ float sval[KACT];
  if (tid < KACT) {
    sidx[tid] = tk_idx[(size_t)b * KACT + tid];
    sval[tid] = tk_val[(size_t)b * KACT + tid];
  }
  __syncthreads();
  f32x4 acc = {0.f, 0.f, 0.f, 0.f};
  for (int k = 0; k < KACT; ++k) {
    const u16x4 w4 = *(const u16x4*)(WdT_b + (size_t)sidx[k] * IN_DIM + tid * 4);
    const float v = sval[k];
    acc[0] = fmaf(v, bf2f(w4[0]), acc[0]);
    acc[1] = fmaf(v, bf2f(w4[1]), acc[1]);
    acc[2] = fmaf(v, bf2f(w4[2]), acc[2]);
    acc[3] = fmaf(v, bf2f(w4[3]), acc[3]);
  }
  __builtin_nontemporal_store(acc, (f32x4*)(out + (size_t)b * IN_DIM + tid * 4));
}

// ---------------------------------------------------------------------------
// W_dec [IN_DIM][HID] f32 -> W_decT [HID][IN_DIM] bf16
// ---------------------------------------------------------------------------
__global__ __launch_bounds__(256) void transpose_wdec(const float* __restrict__ Wd,
                                                      uint16_t* __restrict__ WdT_b) {
  __shared__ float t[32][33];
  const int tx = threadIdx.x & 31;
  const int ty = threadIdx.x >> 5;
  const int hb = blockIdx.x * 32;
  const int ib = blockIdx.y * 32;
#pragma unroll
  for (int r = ty; r < 32; r += 8)
    t[r][tx] = Wd[(size_t)(ib + r) * HID + hb + tx];
  __syncthreads();
  const int tx2 = threadIdx.x & 15;
  const int ty2 = threadIdx.x >> 4;
#pragma unroll
  for (int c = ty2; c < 32; c += 16) {
    uint32_t pk = (uint32_t)f2bf(t[2 * tx2][c]) |
                  ((uint32_t)f2bf(t[2 * tx2 + 1][c]) << 16);
    *(uint32_t*)(WdT_b + (size_t)(hb + c) * IN_DIM + ib + 2 * tx2) = pk;
  }
}

// ---------------------------------------------------------------------------
// Fallback (r3-proven): fp32 vector GEMM + radix topk + gather decoder
// ---------------------------------------------------------------------------
__global__ __launch_bounds__(256) void enc_gemm(const float* __restrict__ A,
                                                const float* __restrict__ Bw,
                                                float* __restrict__ C) {
  __shared__ float As[16][132];
  __shared__ float Bs[16][132];
  const int tid = threadIdx.x;
  const int bm = blockIdx.y;
  const int bn = blockIdx.x;
  const int m0 = (tid >> 4) << 3;
  const int n0 = (tid & 15) << 3;
  float tot[8][8] = {};
  float acc[8][8] = {};
  const float* Ablk = A + (size_t)bm * 128 * IN_DIM;
  const float* Bblk = Bw + (size_t)bn * 128 * IN_DIM;
  for (int k0 = 0; k0 < IN_DIM; k0 += 16) {
#pragma unroll
    for (int l = 0; l < 2; ++l) {
      int li = tid + l * 256;
      int row = li >> 2;
      int c4 = (li & 3) << 2;
      float4 va = *reinterpret_cast<const float4*>(Ablk + (size_t)row * IN_DIM + k0 + c4);
      As[c4 + 0][row] = va.x; As[c4 + 1][row] = va.y;
      As[c4 + 2][row] = va.z; As[c4 + 3][row] = va.w;
      float4 vb = *reinterpret_cast<const float4*>(Bblk + (size_t)row * IN_DIM + k0 + c4);
      Bs[c4 + 0][row] = vb.x; Bs[c4 + 1][row] = vb.y;
      Bs[c4 + 2][row] = vb.z; Bs[c4 + 3][row] = vb.w;
    }
    __syncthreads();
#pragma unroll
    for (int kk = 0; kk < 16; ++kk) {
      float a[8], b[8];
#pragma unroll
      for (int i = 0; i < 8; ++i) a[i] = As[kk][m0 + i];
#pragma unroll
      for (int j = 0; j < 8; ++j) b[j] = Bs[kk][n0 + j];
#pragma unroll
      for (int i = 0; i < 8; ++i)
#pragma unroll
        for (int j = 0; j < 8; ++j) acc[i][j] = fmaf(a[i], b[j], acc[i][j]);
    }
    __syncthreads();
    const int kend = k0 + 16;
    if (kend == 384 || kend == 768 || kend == IN_DIM) {
#pragma unroll
      for (int i = 0; i < 8; ++i)
#pragma unroll
        for (int j = 0; j < 8; ++j) { tot[i][j] += acc[i][j]; acc[i][j] = 0.0f; }
    }
  }
  float* Cblk = C + (size_t)(bm * 128) * HID + bn * 128;
#pragma unroll
  for (int i = 0; i < 8; ++i) {
    float4 v0 = make_float4(tot[i][0], tot[i][1], tot[i][2], tot[i][3]);
    float4 v1 = make_float4(tot[i][4], tot[i][5], tot[i][6], tot[i][7]);
    *reinterpret_cast<float4*>(Cblk + (size_t)(m0 + i) * HID + n0) = v0;
    *reinterpret_cast<float4*>(Cblk + (size_t)(m0 + i) * HID + n0 + 4) = v1;
  }
}

__global__ __launch_bounds__(256) void topk_kernel(float* __restrict__ enc,
                                                   int* __restrict__ tk_idx,
                                                   float* __restrict__ tk_val) {
  const int b = blockIdx.x;
  const int tid = threadIdx.x;
  float* row = enc + (size_t)b * HID;
  uint32_t keys[64];
#pragma unroll
  for (int i = 0; i < 64; ++i) keys[i] = fmap(row[tid + (i << 8)]);
  __shared__ uint32_t hist[256];
  __shared__ uint32_t sfx[256];
  __shared__ uint32_t s_prefix, s_krem;
  __shared__ int eqidx[256];
  __shared__ uint32_t eqcnt;
  if (tid == 0) { s_prefix = 0u; s_krem = KACT; }
  for (int pass = 0; pass < 4; ++pass) {
    const int shift = 24 - pass * 8;
    hist[tid] = 0;
    __syncthreads();
    const uint32_t pm = pass ? (0xFFFFFFFFu << (shift + 8)) : 0u;
    const uint32_t prefix = s_prefix;
#pragma unroll
    for (int i = 0; i < 64; ++i)
      if ((keys[i] & pm) == prefix) atomicAdd(&hist[(keys[i] >> shift) & 255], 1u);
    __syncthreads();
    sfx[tid] = hist[tid];
    __syncthreads();
    for (int d = 1; d < 256; d <<= 1) {
      uint32_t add = (tid + d < 256) ? sfx[tid + d] : 0u;
      __syncthreads();
      sfx[tid] += add;
      __syncthreads();
    }
    const uint32_t krem = s_krem;
    __syncthreads();
    const uint32_t above = sfx[tid] - hist[tid];
    if (above < krem && sfx[tid] >= krem) {
      s_prefix = prefix | ((uint32_t)tid << shift);
      s_krem = krem - above;
    }
    __syncthreads();
  }
  const uint32_t T = s_prefix;
  const uint32_t take_eq = s_krem;
  if (tid == 0) eqcnt = 0;
  __syncthreads();
#pragma unroll
  for (int i = 0; i < 64; ++i)
    if (keys[i] == T) {
      uint32_t p = atomicAdd(&eqcnt, 1u);
      if (p < 256u) eqidx[p] = tid + (i << 8);
    }
  __syncthreads();
  if (tid == 0) {
    int n = (int)min(eqcnt, 256u);
    for (int a = 1; a < n; ++a) {
      int v = eqidx[a]; int c = a - 1;
      while (c >= 0 && eqidx[c] > v) { eqidx[c + 1] = eqidx[c]; --c; }
      eqidx[c + 1] = v;
    }
  }
  __syncthreads();
  uint64_t keepm = 0ull;
  uint32_t cnt = 0;
#pragma unroll
  for (int i = 0; i < 64; ++i) {
    const int idx = tid + (i << 8);
    const uint32_t u = keys[i];
    bool keep = (u > T);
    if (u == T) {
      for (uint32_t e = 0; e < take_eq; ++e)
        if (eqidx[e] == idx) { keep = true; break; }
    }
    if (keep) { keepm |= (1ull << i); ++cnt; }
  }
  sfx[tid] = cnt;
  __syncthreads();
  for (int d = 1; d < 256; d <<= 1) {
    uint32_t add = (tid >= d) ? sfx[tid - d] : 0u;
    __syncthreads();
    sfx[tid] += add;
    __syncthreads();
  }
  uint32_t pos = sfx[tid] - cnt;
#pragma unroll
  for (int i = 0; i < 64; ++i) {
    const int idx = tid + (i << 8);
    const uint32_t u = keys[i];
    const uint32_t sbits = (u & 0x80000000u) ? (u ^ 0x80000000u) : ~u;
    const float f = __uint_as_float(sbits);
    const bool keep = (keepm >> i) & 1ull;
    row[idx] = keep ? f : 0.0f;
    if (keep) {
      tk_idx[(size_t)b * KACT + pos] = idx;
      tk_val[(size_t)b * KACT + pos] = f;
      ++pos;
    }
  }
}

__global__ __launch_bounds__(256) void decoder_g(const int* __restrict__ tk_idx,
                                                 const float* __restrict__ tk_val,
                                                 const float* __restrict__ Wd,
                                                 float* __restrict__ out) {
  const int b = blockIdx.x;
  const int tid = threadIdx.x;
  __shared__ int sidx[KACT];
  __shared__ float sval[KACT];
  if (tid < KACT) {
    sidx[tid] = tk_idx[(size_t)b * KACT + tid];
    sval[tid] = tk_val[(size_t)b * KACT + tid];
  }
  __syncthreads();
  float acc[4] = {0.f, 0.f, 0.f, 0.f};
  for (int k = 0; k < KACT; ++k) {
    const int h = sidx[k];
    const float v = sval[k];
#pragma unroll
    for (int j = 0; j < 4; ++j)
      acc[j] = fmaf(v, Wd[(size_t)(tid + j * 256) * HID + h], acc[j]);
  }
#pragma unroll
  for (int j = 0; j < 4; ++j) out[(size_t)b * IN_DIM + tid + j * 256] = acc[j];
}

// ---------------------------------------------------------------------------
extern "C" void kernel_launch(void* const* d_in, const int* in_sizes, int n_in,
                              void* d_out, int out_size, void* d_ws, size_t ws_size,
                              hipStream_t stream) {
  const float* x = (const float*)d_in[0];
  const float* Wenc = (const float*)d_in[1];
  const float* Wdec = (const float*)d_in[2];
  float* out = (float*)d_out;
  float* decoded = out;
  float* sparse = out + (size_t)BATCH * IN_DIM;

  const size_t MB = 1024ull * 1024ull;
  char* ws = (char*)d_ws;
  int*   tk_idx    = (int*)(ws + 0 * MB);
  float* tk_val    = (float*)(ws + 1 * MB);
  int*   cand_idx  = (int*)(ws + 2 * MB);
  float* cand_aval = (float*)(ws + 4 * MB);
  int*   row_cnt   = (int*)(ws + 6 * MB);
  int*   row_need  = (int*)(ws + 6 * MB + 65536);
  uint16_t* A2     = (uint16_t*)(ws + 8 * MB);
  uint16_t* B2     = (uint16_t*)(ws + 16 * MB);
  uint16_t* WdT_b  = (uint16_t*)(ws + 48 * MB);

  const size_t need_new = 80 * MB;

  if (ws_size >= need_new) {
    convert_bf16<<<1024, 256, 0, stream>>>(x, A2, (size_t)BATCH * IN_DIM / 4);
    convert_bf16<<<2048, 256, 0, stream>>>(Wenc, B2, (size_t)HID * IN_DIM / 4);
    mfma_gemm<<<4096, 256, 0, stream>>>(A2, B2, (uint16_t*)sparse);
    transpose_wdec<<<dim3(HID / 32, IN_DIM / 32), 256, 0, stream>>>(Wdec, WdT_b);
    select_bin<<<BATCH, 256, 0, stream>>>(sparse, tk_idx, tk_val, cand_idx,
                                          cand_aval, row_cnt, row_need);
    exact_patch<<<BATCH, 192, 0, stream>>>(x, Wenc, cand_idx, cand_aval,
                                           row_cnt, row_need, sparse,
                                           tk_idx, tk_val);
    decoder_t<<<BATCH, 256, 0, stream>>>(tk_idx, tk_val, WdT_b, decoded);
  } else {
    enc_gemm<<<dim3(HID / 128, BATCH / 128), 256, 0, stream>>>(x, Wenc, sparse);
    topk_kernel<<<BATCH, 256, 0, stream>>>(sparse, tk_idx, tk_val);
    decoder_g<<<BATCH, 256, 0, stream>>>(tk_idx, tk_val, Wdec, decoded);
  }
}

// Round 15
// 505.275 us; speedup vs baseline: 1.1334x; 1.0980x over previous
//
#include <hip/hip_runtime.h>
#include <stdint.h>

#define BATCH 4096
#define IN_DIM 1024
#define HID 16384
#define KACT 64
#define EPS2 0.08f   // margin; |bf16(v_mfma) - v_np| <= ~0.035 < EPS2 window proof (r7)
#define CCAP 128

typedef short bf16x8 __attribute__((ext_vector_type(8)));
typedef short short8 __attribute__((ext_vector_type(8)));
typedef unsigned short u16x4 __attribute__((ext_vector_type(4)));
typedef float f32x4 __attribute__((ext_vector_type(4)));

__device__ __forceinline__ uint16_t f2bf(float f) {
  uint32_t u = __float_as_uint(f);
  return (uint16_t)((u + 0x7FFFu + ((u >> 16) & 1u)) >> 16);
}
__device__ __forceinline__ float bf2f(uint16_t h) {
  return __uint_as_float((uint32_t)h << 16);
}
__device__ __forceinline__ uint32_t fmap(float f) {
  uint32_t u = __float_as_uint(f);
  return (u & 0x80000000u) ? ~u : (u | 0x80000000u);
}
__device__ __forceinline__ void gload_lds16(const void* g, void* l) {
  __builtin_amdgcn_global_load_lds(
      (const __attribute__((address_space(1))) unsigned int*)g,
      (__attribute__((address_space(3))) unsigned int*)l, 16, 0, 0);
}

// ---------------------------------------------------------------------------
// Plain bf16 cast: out[i] = bf16(in[i]), 4 elems/thread
// ---------------------------------------------------------------------------
__global__ __launch_bounds__(256) void convert_bf16(const float* __restrict__ in,
                                                    uint16_t* __restrict__ out,
                                                    size_t n4) {
  for (size_t i = (size_t)blockIdx.x * 256 + threadIdx.x; i < n4;
       i += (size_t)gridDim.x * 256) {
    f32x4 v = *(const f32x4*)(in + i * 4);
    uint64_t pk = (uint64_t)f2bf(v[0]) | ((uint64_t)f2bf(v[1]) << 16) |
                  ((uint64_t)f2bf(v[2]) << 32) | ((uint64_t)f2bf(v[3]) << 48);
    *(uint64_t*)(out + i * 4) = pk;
  }
}

// ---------------------------------------------------------------------------
// bf16 MFMA GEMM, 128x128 tile, BK=64, K=1024, XCD-grouped order.
// 2-phase double-buffered LDS; swapped MFMA operands -> packed 8B bf16 stores
// (regular stores: C needs L2 residency for select_bin's read — r14 lesson).
// s_setprio(1) around MFMA clusters (T5).
// ---------------------------------------------------------------------------
__global__ __launch_bounds__(256) void mfma_gemm(const uint16_t* __restrict__ A2,
                                                 const uint16_t* __restrict__ B2,
                                                 uint16_t* __restrict__ Cb) {
  __shared__ __attribute__((aligned(16))) char lds[2][32768];
  const int tid = threadIdx.x;
  const int lane = tid & 63;
  const int wave = tid >> 6;
  const int wr = wave >> 1, wc = wave & 1;

  const int bid = blockIdx.x;
  const int xcd = bid & 7;
  const int pos = bid >> 3;
  const int g = pos >> 4;
  const int rem = pos & 15;
  const int bm = xcd * 4 + (rem >> 2);
  const int bn = g * 4 + (rem & 3);

  const char* Abase = (const char*)(A2 + (size_t)(bm * 128) * IN_DIM);
  const char* Bbase = (const char*)(B2 + (size_t)(bn * 128) * IN_DIM);

  const int srow = lane >> 3;
  const int scolb = (lane & 7) << 4;

  auto stage = [&](int kt, int buf) {
    const int colB = kt * 128;
#pragma unroll
    for (int j = 0; j < 4; ++j) {
      const int r0 = wave * 32 + j * 8;
      const int row = r0 + srow;
      const int swz = (row & 7) << 4;
      gload_lds16(Abase + (size_t)row * 2048 + colB + (scolb ^ swz),
                  lds[buf] + r0 * 128);
      gload_lds16(Bbase + (size_t)row * 2048 + colB + (scolb ^ swz),
                  lds[buf] + 16384 + r0 * 128);
    }
  };

  f32x4 acc[4][4] = {};

  stage(0, 0);
  __syncthreads();

  for (int kt = 0; kt < 16; ++kt) {
    const int buf = kt & 1;
    if (kt < 15) stage(kt + 1, buf ^ 1);

#pragma unroll
    for (int ku = 0; ku < 2; ++ku) {
      bf16x8 af[4], bf_[4];
      const int kb = ku * 64 + ((lane >> 4) << 4);
#pragma unroll
      for (int m = 0; m < 4; ++m) {
        const int row = wr * 64 + m * 16 + (lane & 15);
        af[m] = *(const bf16x8*)(lds[buf] + row * 128 + (kb ^ ((row & 7) << 4)));
      }
#pragma unroll
      for (int n = 0; n < 4; ++n) {
        const int row = wc * 64 + n * 16 + (lane & 15);
        bf_[n] = *(const bf16x8*)(lds[buf] + 16384 + row * 128 +
                                  (kb ^ ((row & 7) << 4)));
      }
      __builtin_amdgcn_s_setprio(1);
#pragma unroll
      for (int m = 0; m < 4; ++m)
#pragma unroll
        for (int n = 0; n < 4; ++n)
          acc[m][n] = __builtin_amdgcn_mfma_f32_16x16x32_bf16(bf_[n], af[m],
                                                              acc[m][n], 0, 0, 0);
      __builtin_amdgcn_s_setprio(0);
    }
    __syncthreads();
  }

#pragma unroll
  for (int m = 0; m < 4; ++m) {
    const int grow = bm * 128 + wr * 64 + m * 16 + (lane & 15);
    uint16_t* rowp = Cb + (size_t)grow * (2 * HID);
#pragma unroll
    for (int n = 0; n < 4; ++n) {
      const int gcol0 = bn * 128 + wc * 64 + n * 16 + ((lane >> 4) << 2);
      uint2 pk;
      pk.x = (uint32_t)f2bf(acc[m][n][0]) | ((uint32_t)f2bf(acc[m][n][1]) << 16);
      pk.y = (uint32_t)f2bf(acc[m][n][2]) | ((uint32_t)f2bf(acc[m][n][3]) << 16);
      *(uint2*)(rowp + gcol0) = pk;
    }
  }
}

// ---------------------------------------------------------------------------
// select_bin (512 threads, 32 vals/thread): reads bf16 C, binary-search
// threshold bracket (11 iters), classifies sure/window, writes full f32
// sparse row, emits compact sure list + window candidates + per-row meta.
// ---------------------------------------------------------------------------
__global__ __launch_bounds__(512) void select_bin(float* __restrict__ enc,
                                                  int* __restrict__ tk_idx,
                                                  float* __restrict__ tk_val,
                                                  int* __restrict__ cand_idx,
                                                  float* __restrict__ cand_aval,
                                                  int* __restrict__ row_cnt,
                                                  int* __restrict__ row_need) {
  const int b = blockIdx.x;
  const int tid = threadIdx.x;        // 0..511
  const int lane = tid & 63;
  const int wid = tid >> 6;           // 0..7
  float* rowf = enc + (size_t)b * HID;
  const uint16_t* rb = (const uint16_t*)rowf;

  float vals[32];
#pragma unroll
  for (int i = 0; i < 4; ++i) {
    short8 v8 = *(const short8*)(rb + tid * 8 + i * 4096);
#pragma unroll
    for (int j = 0; j < 8; ++j) vals[i * 8 + j] = bf2f((uint16_t)v8[j]);
  }

  // ---- binary search bracket: count(v > hi) < 64 <= count(v > lo) ----
  __shared__ uint32_t wsum[2][8];
  float lo = -16.0f, hi = 16.0f;
  for (int it = 0; it < 11; ++it) {
    const float mid = 0.5f * (lo + hi);
    uint32_t c = 0;
#pragma unroll
    for (int q = 0; q < 32; ++q) c += (vals[q] > mid);
#pragma unroll
    for (int d = 1; d < 64; d <<= 1) c += __shfl_xor(c, d, 64);
    if (lane == 0) wsum[it & 1][wid] = c;
    __syncthreads();
    uint32_t tot = 0;
#pragma unroll
    for (int w = 0; w < 8; ++w) tot += wsum[it & 1][w];
    if (tot >= (uint32_t)KACT) lo = mid; else hi = mid;
  }

  const float sure_thr = hi + EPS2;
  const float cand_lo = lo - EPS2;

  // ---- classify ----
  __shared__ uint32_t bitmap[HID / 32];   // 512 words, 1 per thread
  __shared__ uint32_t s_nc, s_cs;
  bitmap[tid] = 0u;
  if (tid == 0) { s_nc = 0u; s_cs = 0u; }
  __syncthreads();

  uint32_t cs = 0;
#pragma unroll
  for (int i = 0; i < 4; ++i)
#pragma unroll
    for (int j = 0; j < 8; ++j) {
      const float v = vals[i * 8 + j];
      const int idx = tid * 8 + i * 4096 + j;
      if (v > sure_thr) {
        ++cs;
        atomicOr(&bitmap[idx >> 5], 1u << (idx & 31));
      } else if (v >= cand_lo) {
        uint32_t p = atomicAdd(&s_nc, 1u);
        if (p < CCAP) {
          cand_idx[(size_t)b * CCAP + p] = idx;
          cand_aval[(size_t)b * CCAP + p] = v;
        }
      }
    }
#pragma unroll
  for (int d = 1; d < 64; d <<= 1) cs += __shfl_xor(cs, d, 64);
  if (lane == 0) atomicAdd(&s_cs, cs);
  __syncthreads();

  if (tid == 0) {
    row_cnt[b] = (int)min(s_nc, (uint32_t)CCAP);
    row_need[b] = KACT - (int)s_cs;   // >= 1 by bracket invariant
  }

  // ---- write full f32 sparse row + compact sure list ----
  uint32_t keepm = 0u;
  uint32_t c2 = 0;
#pragma unroll
  for (int i = 0; i < 4; ++i) {
    f32x4 o0, o1;
#pragma unroll
    for (int j = 0; j < 8; ++j) {
      const int idx = tid * 8 + i * 4096 + j;
      const float v = vals[i * 8 + j];
      const bool keep = (bitmap[idx >> 5] >> (idx & 31)) & 1u;
      const float ov = keep ? v : 0.0f;
      if (j < 4) o0[j] = ov; else o1[j - 4] = ov;
      if (keep) { keepm |= (1u << (i * 8 + j)); ++c2; }
    }
    *(f32x4*)(rowf + tid * 8 + i * 4096) = o0;
    *(f32x4*)(rowf + tid * 8 + i * 4096 + 4) = o1;
  }
  __shared__ uint32_t psum[8];
  uint32_t p = c2;
#pragma unroll
  for (int d = 1; d < 64; d <<= 1) {
    uint32_t o = __shfl_up(p, d, 64);
    if (lane >= d) p += o;
  }
  if (lane == 63) psum[wid] = p;
  __syncthreads();
  uint32_t off = 0;
  for (int w = 0; w < wid; ++w) off += psum[w];
  uint32_t posn = off + p - c2;
#pragma unroll
  for (int i = 0; i < 4; ++i)
#pragma unroll
    for (int j = 0; j < 8; ++j) {
      if ((keepm >> (i * 8 + j)) & 1u) {
        if (posn < KACT) {
          tk_idx[(size_t)b * KACT + posn] = tid * 8 + i * 4096 + j;
          tk_val[(size_t)b * KACT + posn] = vals[i * 8 + j];
        }
        ++posn;
      }
    }
}

// ---------------------------------------------------------------------------
// exact_patch: 192 threads = 3 waves; thread (c = t&63, p = t>>6) computes
// panel p of candidate c (sequential k-ascending fp32 chain, Kc=384 breaks —
// r3-proven np scheme); rank (val desc, idx asc); winners patch sparse row
// and fill tk slots [KACT-need, KACT).
// ---------------------------------------------------------------------------
__global__ __launch_bounds__(192) void exact_patch(const float* __restrict__ x,
                                                   const float* __restrict__ Wenc,
                                                   const int* __restrict__ cand_idx,
                                                   const float* __restrict__ cand_aval,
                                                   const int* __restrict__ row_cnt,
                                                   const int* __restrict__ row_need,
                                                   float* __restrict__ enc,
                                                   int* __restrict__ tk_idx,
                                                   float* __restrict__ tk_val) {
  const int b = blockIdx.x;
  const int t = threadIdx.x;
  __shared__ float xs[IN_DIM];
  for (int i = t; i < IN_DIM / 4; i += 192)
    *(f32x4*)(xs + i * 4) = *(const f32x4*)(x + (size_t)b * IN_DIM + i * 4);

  const int cnt = row_cnt[b];
  const int need = row_need[b];
  __shared__ int eidx[CCAP];
  __shared__ float eaval[CCAP];
  __shared__ float spp[CCAP][3];
  __shared__ float evals[CCAP];
  for (int c = t; c < cnt; c += 192) {
    eidx[c] = cand_idx[(size_t)b * CCAP + c];
    eaval[c] = cand_aval[(size_t)b * CCAP + c];
  }
  __syncthreads();

  const int p = t >> 6;            // panel 0..2
  const int lane = t & 63;
  const int k0 = p * 384;
  const int k1 = (p == 2) ? 1024 : (k0 + 384);

  for (int c = lane; c < cnt; c += 64) {
    const float* w = Wenc + (size_t)eidx[c] * IN_DIM;
    float acc = 0.f;
    for (int k = k0; k < k1; k += 16) {
      const f32x4 w0 = *(const f32x4*)(w + k);
      const f32x4 w1 = *(const f32x4*)(w + k + 4);
      const f32x4 w2 = *(const f32x4*)(w + k + 8);
      const f32x4 w3 = *(const f32x4*)(w + k + 12);
#pragma unroll
      for (int j = 0; j < 4; ++j) acc = fmaf(xs[k + j], w0[j], acc);
#pragma unroll
      for (int j = 0; j < 4; ++j) acc = fmaf(xs[k + 4 + j], w1[j], acc);
#pragma unroll
      for (int j = 0; j < 4; ++j) acc = fmaf(xs[k + 8 + j], w2[j], acc);
#pragma unroll
      for (int j = 0; j < 4; ++j) acc = fmaf(xs[k + 12 + j], w3[j], acc);
    }
    spp[c][p] = acc;
  }
  __syncthreads();
  if (t < cnt) evals[t] = (spp[t][0] + spp[t][1]) + spp[t][2];
  __syncthreads();

  if (t < cnt && need > 0) {
    const float e = evals[t];
    const int myidx = eidx[t];
    int rank = 0;
    for (int c = 0; c < cnt; ++c)
      rank += (evals[c] > e) || (evals[c] == e && eidx[c] < myidx);
    if (rank < need) {
      const float v = eaval[t];
      enc[(size_t)b * HID + myidx] = v;
      const int slot = (KACT - need) + rank;
      tk_idx[(size_t)b * KACT + slot] = myidx;
      tk_val[(size_t)b * KACT + slot] = v;
    }
  }
}

// ---------------------------------------------------------------------------
// decoder_t: decoded[b,:] = sum_k val_k * WdT_b[idx_k,:] (bf16 weights)
// ---------------------------------------------------------------------------
__global__ __launch_bounds__(256) void decoder_t(const int* __restrict__ tk_idx,
                                                 const float* __restrict__ tk_val,
                                                 const uint16_t* __restrict__ WdT_b,
                                                 float* __restrict__ out) {
  const int b = blockIdx.x;
  const int tid = threadIdx.x;
  __shared__ int sidx[KACT];
  __shared__ float sval[KACT];
  if (tid < KACT) {
    sidx[tid] = tk_idx[(size_t)b * KACT + tid];
    sval[tid] = tk_val[(size_t)b * KACT + tid];
  }
  __syncthreads();
  f32x4 acc = {0.f, 0.f, 0.f, 0.f};
  for (int k = 0; k < KACT; ++k) {
    const u16x4 w4 = *(const u16x4*)(WdT_b + (size_t)sidx[k] * IN_DIM + tid * 4);
    const float v = sval[k];
    acc[0] = fmaf(v, bf2f(w4[0]), acc[0]);
    acc[1] = fmaf(v, bf2f(w4[1]), acc[1]);
    acc[2] = fmaf(v, bf2f(w4[2]), acc[2]);
    acc[3] = fmaf(v, bf2f(w4[3]), acc[3]);
  }
  *(f32x4*)(out + (size_t)b * IN_DIM + tid * 4) = acc;
}

// ---------------------------------------------------------------------------
// W_dec [IN_DIM][HID] f32 -> W_decT [HID][IN_DIM] bf16
// ---------------------------------------------------------------------------
__global__ __launch_bounds__(256) void transpose_wdec(const float* __restrict__ Wd,
                                                      uint16_t* __restrict__ WdT_b) {
  __shared__ float t[32][33];
  const int tx = threadIdx.x & 31;
  const int ty = threadIdx.x >> 5;
  const int hb = blockIdx.x * 32;
  const int ib = blockIdx.y * 32;
#pragma unroll
  for (int r = ty; r < 32; r += 8)
    t[r][tx] = Wd[(size_t)(ib + r) * HID + hb + tx];
  __syncthreads();
  const int tx2 = threadIdx.x & 15;
  const int ty2 = threadIdx.x >> 4;
#pragma unroll
  for (int c = ty2; c < 32; c += 16) {
    uint32_t pk = (uint32_t)f2bf(t[2 * tx2][c]) |
                  ((uint32_t)f2bf(t[2 * tx2 + 1][c]) << 16);
    *(uint32_t*)(WdT_b + (size_t)(hb + c) * IN_DIM + ib + 2 * tx2) = pk;
  }
}

// ---------------------------------------------------------------------------
// Fallback (r3-proven): fp32 vector GEMM + radix topk + gather decoder
// ---------------------------------------------------------------------------
__global__ __launch_bounds__(256) void enc_gemm(const float* __restrict__ A,
                                                const float* __restrict__ Bw,
                                                float* __restrict__ C) {
  __shared__ float As[16][132];
  __shared__ float Bs[16][132];
  const int tid = threadIdx.x;
  const int bm = blockIdx.y;
  const int bn = blockIdx.x;
  const int m0 = (tid >> 4) << 3;
  const int n0 = (tid & 15) << 3;
  float tot[8][8] = {};
  float acc[8][8] = {};
  const float* Ablk = A + (size_t)bm * 128 * IN_DIM;
  const float* Bblk = Bw + (size_t)bn * 128 * IN_DIM;
  for (int k0 = 0; k0 < IN_DIM; k0 += 16) {
#pragma unroll
    for (int l = 0; l < 2; ++l) {
      int li = tid + l * 256;
      int row = li >> 2;
      int c4 = (li & 3) << 2;
      float4 va = *reinterpret_cast<const float4*>(Ablk + (size_t)row * IN_DIM + k0 + c4);
      As[c4 + 0][row] = va.x; As[c4 + 1][row] = va.y;
      As[c4 + 2][row] = va.z; As[c4 + 3][row] = va.w;
      float4 vb = *reinterpret_cast<const float4*>(Bblk + (size_t)row * IN_DIM + k0 + c4);
      Bs[c4 + 0][row] = vb.x; Bs[c4 + 1][row] = vb.y;
      Bs[c4 + 2][row] = vb.z; Bs[c4 + 3][row] = vb.w;
    }
    __syncthreads();
#pragma unroll
    for (int kk = 0; kk < 16; ++kk) {
      float a[8], b[8];
#pragma unroll
      for (int i = 0; i < 8; ++i) a[i] = As[kk][m0 + i];
#pragma unroll
      for (int j = 0; j < 8; ++j) b[j] = Bs[kk][n0 + j];
#pragma unroll
      for (int i = 0; i < 8; ++i)
#pragma unroll
        for (int j = 0; j < 8; ++j) acc[i][j] = fmaf(a[i], b[j], acc[i][j]);
    }
    __syncthreads();
    const int kend = k0 + 16;
    if (kend == 384 || kend == 768 || kend == IN_DIM) {
#pragma unroll
      for (int i = 0; i < 8; ++i)
#pragma unroll
        for (int j = 0; j < 8; ++j) { tot[i][j] += acc[i][j]; acc[i][j] = 0.0f; }
    }
  }
  float* Cblk = C + (size_t)(bm * 128) * HID + bn * 128;
#pragma unroll
  for (int i = 0; i < 8; ++i) {
    float4 v0 = make_float4(tot[i][0], tot[i][1], tot[i][2], tot[i][3]);
    float4 v1 = make_float4(tot[i][4], tot[i][5], tot[i][6], tot[i][7]);
    *reinterpret_cast<float4*>(Cblk + (size_t)(m0 + i) * HID + n0) = v0;
    *reinterpret_cast<float4*>(Cblk + (size_t)(m0 + i) * HID + n0 + 4) = v1;
  }
}

__global__ __launch_bounds__(256) void topk_kernel(float* __restrict__ enc,
                                                   int* __restrict__ tk_idx,
                                                   float* __restrict__ tk_val) {
  const int b = blockIdx.x;
  const int tid = threadIdx.x;
  float* row = enc + (size_t)b * HID;
  uint32_t keys[64];
#pragma unroll
  for (int i = 0; i < 64; ++i) keys[i] = fmap(row[tid + (i << 8)]);
  __shared__ uint32_t hist[256];
  __shared__ uint32_t sfx[256];
  __shared__ uint32_t s_prefix, s_krem;
  __shared__ int eqidx[256];
  __shared__ uint32_t eqcnt;
  if (tid == 0) { s_prefix = 0u; s_krem = KACT; }
  for (int pass = 0; pass < 4; ++pass) {
    const int shift = 24 - pass * 8;
    hist[tid] = 0;
    __syncthreads();
    const uint32_t pm = pass ? (0xFFFFFFFFu << (shift + 8)) : 0u;
    const uint32_t prefix = s_prefix;
#pragma unroll
    for (int i = 0; i < 64; ++i)
      if ((keys[i] & pm) == prefix) atomicAdd(&hist[(keys[i] >> shift) & 255], 1u);
    __syncthreads();
    sfx[tid] = hist[tid];
    __syncthreads();
    for (int d = 1; d < 256; d <<= 1) {
      uint32_t add = (tid + d < 256) ? sfx[tid + d] : 0u;
      __syncthreads();
      sfx[tid] += add;
      __syncthreads();
    }
    const uint32_t krem = s_krem;
    __syncthreads();
    const uint32_t above = sfx[tid] - hist[tid];
    if (above < krem && sfx[tid] >= krem) {
      s_prefix = prefix | ((uint32_t)tid << shift);
      s_krem = krem - above;
    }
    __syncthreads();
  }
  const uint32_t T = s_prefix;
  const uint32_t take_eq = s_krem;
  if (tid == 0) eqcnt = 0;
  __syncthreads();
#pragma unroll
  for (int i = 0; i < 64; ++i)
    if (keys[i] == T) {
      uint32_t p = atomicAdd(&eqcnt, 1u);
      if (p < 256u) eqidx[p] = tid + (i << 8);
    }
  __syncthreads();
  if (tid == 0) {
    int n = (int)min(eqcnt, 256u);
    for (int a = 1; a < n; ++a) {
      int v = eqidx[a]; int c = a - 1;
      while (c >= 0 && eqidx[c] > v) { eqidx[c + 1] = eqidx[c]; --c; }
      eqidx[c + 1] = v;
    }
  }
  __syncthreads();
  uint64_t keepm = 0ull;
  uint32_t cnt = 0;
#pragma unroll
  for (int i = 0; i < 64; ++i) {
    const int idx = tid + (i << 8);
    const uint32_t u = keys[i];
    bool keep = (u > T);
    if (u == T) {
      for (uint32_t e = 0; e < take_eq; ++e)
        if (eqidx[e] == idx) { keep = true; break; }
    }
    if (keep) { keepm |= (1ull << i); ++cnt; }
  }
  sfx[tid] = cnt;
  __syncthreads();
  for (int d = 1; d < 256; d <<= 1) {
    uint32_t add = (tid >= d) ? sfx[tid - d] : 0u;
    __syncthreads();
    sfx[tid] += add;
    __syncthreads();
  }
  uint32_t pos = sfx[tid] - cnt;
#pragma unroll
  for (int i = 0; i < 64; ++i) {
    const int idx = tid + (i << 8);
    const uint32_t u = keys[i];
    const uint32_t sbits = (u & 0x80000000u) ? (u ^ 0x80000000u) : ~u;
    const float f = __uint_as_float(sbits);
    const bool keep = (keepm >> i) & 1ull;
    row[idx] = keep ? f : 0.0f;
    if (keep) {
      tk_idx[(size_t)b * KACT + pos] = idx;
      tk_val[(size_t)b * KACT + pos] = f;
      ++pos;
    }
  }
}

__global__ __launch_bounds__(256) void decoder_g(const int* __restrict__ tk_idx,
                                                 const float* __restrict__ tk_val,
                                                 const float* __restrict__ Wd,
                                                 float* __restrict__ out) {
  const int b = blockIdx.x;
  const int tid = threadIdx.x;
  __shared__ int sidx[KACT];
  __shared__ float sval[KACT];
  if (tid < KACT) {
    sidx[tid] = tk_idx[(size_t)b * KACT + tid];
    sval[tid] = tk_val[(size_t)b * KACT + tid];
  }
  __syncthreads();
  float acc[4] = {0.f, 0.f, 0.f, 0.f};
  for (int k = 0; k < KACT; ++k) {
    const int h = sidx[k];
    const float v = sval[k];
#pragma unroll
    for (int j = 0; j < 4; ++j)
      acc[j] = fmaf(v, Wd[(size_t)(tid + j * 256) * HID + h], acc[j]);
  }
#pragma unroll
  for (int j = 0; j < 4; ++j) out[(size_t)b * IN_DIM + tid + j * 256] = acc[j];
}

// ---------------------------------------------------------------------------
extern "C" void kernel_launch(void* const* d_in, const int* in_sizes, int n_in,
                              void* d_out, int out_size, void* d_ws, size_t ws_size,
                              hipStream_t stream) {
  const float* x = (const float*)d_in[0];
  const float* Wenc = (const float*)d_in[1];
  const float* Wdec = (const float*)d_in[2];
  float* out = (float*)d_out;
  float* decoded = out;
  float* sparse = out + (size_t)BATCH * IN_DIM;

  const size_t MB = 1024ull * 1024ull;
  char* ws = (char*)d_ws;
  int*   tk_idx    = (int*)(ws + 0 * MB);
  float* tk_val    = (float*)(ws + 1 * MB);
  int*   cand_idx  = (int*)(ws + 2 * MB);
  float* cand_aval = (float*)(ws + 4 * MB);
  int*   row_cnt   = (int*)(ws + 6 * MB);
  int*   row_need  = (int*)(ws + 6 * MB + 65536);
  uint16_t* A2     = (uint16_t*)(ws + 8 * MB);
  uint16_t* B2     = (uint16_t*)(ws + 16 * MB);
  uint16_t* WdT_b  = (uint16_t*)(ws + 48 * MB);

  const size_t need_new = 80 * MB;

  if (ws_size >= need_new) {
    convert_bf16<<<1024, 256, 0, stream>>>(x, A2, (size_t)BATCH * IN_DIM / 4);
    convert_bf16<<<2048, 256, 0, stream>>>(Wenc, B2, (size_t)HID * IN_DIM / 4);
    mfma_gemm<<<4096, 256, 0, stream>>>(A2, B2, (uint16_t*)sparse);
    transpose_wdec<<<dim3(HID / 32, IN_DIM / 32), 256, 0, stream>>>(Wdec, WdT_b);
    select_bin<<<BATCH, 512, 0, stream>>>(sparse, tk_idx, tk_val, cand_idx,
                                          cand_aval, row_cnt, row_need);
    exact_patch<<<BATCH, 192, 0, stream>>>(x, Wenc, cand_idx, cand_aval,
                                           row_cnt, row_need, sparse,
                                           tk_idx, tk_val);
    decoder_t<<<BATCH, 256, 0, stream>>>(tk_idx, tk_val, WdT_b, decoded);
  } else {
    enc_gemm<<<dim3(HID / 128, BATCH / 128), 256, 0, stream>>>(x, Wenc, sparse);
    topk_kernel<<<BATCH, 256, 0, stream>>>(sparse, tk_idx, tk_val);
    decoder_g<<<BATCH, 256, 0, stream>>>(tk_idx, tk_val, Wdec, decoded);
  }
}

// Round 16
// 495.347 us; speedup vs baseline: 1.1561x; 1.0200x over previous
//
#include <hip/hip_runtime.h>
#include <stdint.h>

#define BATCH 4096
#define IN_DIM 1024
#define HID 16384
#define KACT 64
#define EPS2 0.06f   // margin; |bf16(v_mfma) - v_np| <= ~0.035 < EPS2
#define CCAP 128

typedef short bf16x8 __attribute__((ext_vector_type(8)));
typedef short short8 __attribute__((ext_vector_type(8)));
typedef unsigned short u16x4 __attribute__((ext_vector_type(4)));
typedef float f32x4 __attribute__((ext_vector_type(4)));
typedef float f32x16 __attribute__((ext_vector_type(16)));

__device__ __forceinline__ uint16_t f2bf(float f) {
  uint32_t u = __float_as_uint(f);
  return (uint16_t)((u + 0x7FFFu + ((u >> 16) & 1u)) >> 16);
}
__device__ __forceinline__ float bf2f(uint16_t h) {
  return __uint_as_float((uint32_t)h << 16);
}
__device__ __forceinline__ uint32_t fmap(float f) {
  uint32_t u = __float_as_uint(f);
  return (u & 0x80000000u) ? ~u : (u | 0x80000000u);
}
__device__ __forceinline__ void gload_lds16(const void* g, void* l) {
  __builtin_amdgcn_global_load_lds(
      (const __attribute__((address_space(1))) unsigned int*)g,
      (__attribute__((address_space(3))) unsigned int*)l, 16, 0, 0);
}

// ---------------------------------------------------------------------------
// Plain bf16 cast: out[i] = bf16(in[i]), 4 elems/thread
// ---------------------------------------------------------------------------
__global__ __launch_bounds__(256) void convert_bf16(const float* __restrict__ in,
                                                    uint16_t* __restrict__ out,
                                                    size_t n4) {
  for (size_t i = (size_t)blockIdx.x * 256 + threadIdx.x; i < n4;
       i += (size_t)gridDim.x * 256) {
    f32x4 v = *(const f32x4*)(in + i * 4);
    uint64_t pk = (uint64_t)f2bf(v[0]) | ((uint64_t)f2bf(v[1]) << 16) |
                  ((uint64_t)f2bf(v[2]) << 32) | ((uint64_t)f2bf(v[3]) << 48);
    *(uint64_t*)(out + i * 4) = pk;
  }
}

// ---------------------------------------------------------------------------
// bf16 MFMA GEMM, 128x128 tile, BK=64, K=1024, XCD-grouped order.
// 2-phase double-buffered LDS; 32x32x16 MFMA (2x2 tiles/wave, 16 MFMA/K-step
// vs 32 with 16x16x32 — fewer matrix-pipe cycles + half the issue slots).
// Swapped operands: D col = lane&31 -> M row; D row = (reg&3)+8(reg>>2)+
// 4(lane>>5) -> N col (verified 32x32 C/D mapping). Packed 8B bf16 stores.
// ---------------------------------------------------------------------------
__global__ __launch_bounds__(256) void mfma_gemm(const uint16_t* __restrict__ A2,
                                                 const uint16_t* __restrict__ B2,
                                                 uint16_t* __restrict__ Cb) {
  __shared__ __attribute__((aligned(16))) char lds[2][32768];
  const int tid = threadIdx.x;
  const int lane = tid & 63;
  const int wave = tid >> 6;
  const int wr = wave >> 1, wc = wave & 1;

  const int bid = blockIdx.x;
  const int xcd = bid & 7;
  const int pos = bid >> 3;
  const int g = pos >> 4;
  const int rem = pos & 15;
  const int bm = xcd * 4 + (rem >> 2);
  const int bn = g * 4 + (rem & 3);

  const char* Abase = (const char*)(A2 + (size_t)(bm * 128) * IN_DIM);
  const char* Bbase = (const char*)(B2 + (size_t)(bn * 128) * IN_DIM);

  const int srow = lane >> 3;
  const int scolb = (lane & 7) << 4;

  auto stage = [&](int kt, int buf) {
    const int colB = kt * 128;
#pragma unroll
    for (int j = 0; j < 4; ++j) {
      const int r0 = wave * 32 + j * 8;
      const int row = r0 + srow;
      const int swz = (row & 7) << 4;
      gload_lds16(Abase + (size_t)row * 2048 + colB + (scolb ^ swz),
                  lds[buf] + r0 * 128);
      gload_lds16(Bbase + (size_t)row * 2048 + colB + (scolb ^ swz),
                  lds[buf] + 16384 + r0 * 128);
    }
  };

  f32x16 acc[2][2] = {};

  stage(0, 0);
  __syncthreads();

  for (int kt = 0; kt < 16; ++kt) {
    const int buf = kt & 1;
    if (kt < 15) stage(kt + 1, buf ^ 1);

#pragma unroll
    for (int kc = 0; kc < 4; ++kc) {     // four K=16 chunks within BK=64
      bf16x8 af[2], bf_[2];
      const int kb = kc * 32 + ((lane >> 5) << 4);  // byte offset in 128B row
#pragma unroll
      for (int mt = 0; mt < 2; ++mt) {
        const int row = wr * 64 + mt * 32 + (lane & 31);
        af[mt] = *(const bf16x8*)(lds[buf] + row * 128 + (kb ^ ((row & 7) << 4)));
      }
#pragma unroll
      for (int nt = 0; nt < 2; ++nt) {
        const int row = wc * 64 + nt * 32 + (lane & 31);
        bf_[nt] = *(const bf16x8*)(lds[buf] + 16384 + row * 128 +
                                   (kb ^ ((row & 7) << 4)));
      }
      __builtin_amdgcn_s_setprio(1);
#pragma unroll
      for (int mt = 0; mt < 2; ++mt)
#pragma unroll
        for (int nt = 0; nt < 2; ++nt)
          acc[mt][nt] = __builtin_amdgcn_mfma_f32_32x32x16_bf16(
              bf_[nt], af[mt], acc[mt][nt], 0, 0, 0);
      __builtin_amdgcn_s_setprio(0);
    }
    __syncthreads();
  }

  // store: lane&31 -> M row; cols = 8q + 4*(lane>>5) + (0..3) per reg quad q
#pragma unroll
  for (int mt = 0; mt < 2; ++mt) {
    const int grow = bm * 128 + wr * 64 + mt * 32 + (lane & 31);
    uint16_t* rowp = Cb + (size_t)grow * (2 * HID);
#pragma unroll
    for (int nt = 0; nt < 2; ++nt) {
      const int cbase = bn * 128 + wc * 64 + nt * 32 + ((lane >> 5) << 2);
#pragma unroll
      for (int q = 0; q < 4; ++q) {
        const int gcol0 = cbase + 8 * q;
        uint2 pk;
        pk.x = (uint32_t)f2bf(acc[mt][nt][4 * q + 0]) |
               ((uint32_t)f2bf(acc[mt][nt][4 * q + 1]) << 16);
        pk.y = (uint32_t)f2bf(acc[mt][nt][4 * q + 2]) |
               ((uint32_t)f2bf(acc[mt][nt][4 * q + 3]) << 16);
        *(uint2*)(rowp + gcol0) = pk;
      }
    }
  }
}

// ---------------------------------------------------------------------------
// select_bin (512 threads, 32 vals/thread): reads bf16 C, binary-search
// threshold bracket (11 iters), classifies sure/window, writes full f32
// sparse row, emits compact sure list + window candidates + per-row meta.
// ---------------------------------------------------------------------------
__global__ __launch_bounds__(512) void select_bin(float* __restrict__ enc,
                                                  int* __restrict__ tk_idx,
                                                  float* __restrict__ tk_val,
                                                  int* __restrict__ cand_idx,
                                                  float* __restrict__ cand_aval,
                                                  int* __restrict__ row_cnt,
                                                  int* __restrict__ row_need) {
  const int b = blockIdx.x;
  const int tid = threadIdx.x;        // 0..511
  const int lane = tid & 63;
  const int wid = tid >> 6;           // 0..7
  float* rowf = enc + (size_t)b * HID;
  const uint16_t* rb = (const uint16_t*)rowf;

  float vals[32];
#pragma unroll
  for (int i = 0; i < 4; ++i) {
    short8 v8 = *(const short8*)(rb + tid * 8 + i * 4096);
#pragma unroll
    for (int j = 0; j < 8; ++j) vals[i * 8 + j] = bf2f((uint16_t)v8[j]);
  }

  // ---- binary search bracket: count(v > hi) < 64 <= count(v > lo) ----
  __shared__ uint32_t wsum[2][8];
  float lo = -16.0f, hi = 16.0f;
  for (int it = 0; it < 11; ++it) {
    const float mid = 0.5f * (lo + hi);
    uint32_t c = 0;
#pragma unroll
    for (int q = 0; q < 32; ++q) c += (vals[q] > mid);
#pragma unroll
    for (int d = 1; d < 64; d <<= 1) c += __shfl_xor(c, d, 64);
    if (lane == 0) wsum[it & 1][wid] = c;
    __syncthreads();
    uint32_t tot = 0;
#pragma unroll
    for (int w = 0; w < 8; ++w) tot += wsum[it & 1][w];
    if (tot >= (uint32_t)KACT) lo = mid; else hi = mid;
  }

  const float sure_thr = hi + EPS2;
  const float cand_lo = lo - EPS2;

  // ---- classify ----
  __shared__ uint32_t bitmap[HID / 32];   // 512 words, 1 per thread
  __shared__ uint32_t s_nc, s_cs;
  bitmap[tid] = 0u;
  if (tid == 0) { s_nc = 0u; s_cs = 0u; }
  __syncthreads();

  uint32_t cs = 0;
#pragma unroll
  for (int i = 0; i < 4; ++i)
#pragma unroll
    for (int j = 0; j < 8; ++j) {
      const float v = vals[i * 8 + j];
      const int idx = tid * 8 + i * 4096 + j;
      if (v > sure_thr) {
        ++cs;
        atomicOr(&bitmap[idx >> 5], 1u << (idx & 31));
      } else if (v >= cand_lo) {
        uint32_t p = atomicAdd(&s_nc, 1u);
        if (p < CCAP) {
          cand_idx[(size_t)b * CCAP + p] = idx;
          cand_aval[(size_t)b * CCAP + p] = v;
        }
      }
    }
#pragma unroll
  for (int d = 1; d < 64; d <<= 1) cs += __shfl_xor(cs, d, 64);
  if (lane == 0) atomicAdd(&s_cs, cs);
  __syncthreads();

  if (tid == 0) {
    row_cnt[b] = (int)min(s_nc, (uint32_t)CCAP);
    row_need[b] = KACT - (int)s_cs;   // >= 1 by bracket invariant
  }

  // ---- write full f32 sparse row + compact sure list ----
  uint32_t keepm = 0u;
  uint32_t c2 = 0;
#pragma unroll
  for (int i = 0; i < 4; ++i) {
    f32x4 o0, o1;
#pragma unroll
    for (int j = 0; j < 8; ++j) {
      const int idx = tid * 8 + i * 4096 + j;
      const float v = vals[i * 8 + j];
      const bool keep = (bitmap[idx >> 5] >> (idx & 31)) & 1u;
      const float ov = keep ? v : 0.0f;
      if (j < 4) o0[j] = ov; else o1[j - 4] = ov;
      if (keep) { keepm |= (1u << (i * 8 + j)); ++c2; }
    }
    *(f32x4*)(rowf + tid * 8 + i * 4096) = o0;
    *(f32x4*)(rowf + tid * 8 + i * 4096 + 4) = o1;
  }
  __shared__ uint32_t psum[8];
  uint32_t p = c2;
#pragma unroll
  for (int d = 1; d < 64; d <<= 1) {
    uint32_t o = __shfl_up(p, d, 64);
    if (lane >= d) p += o;
  }
  if (lane == 63) psum[wid] = p;
  __syncthreads();
  uint32_t off = 0;
  for (int w = 0; w < wid; ++w) off += psum[w];
  uint32_t posn = off + p - c2;
#pragma unroll
  for (int i = 0; i < 4; ++i)
#pragma unroll
    for (int j = 0; j < 8; ++j) {
      if ((keepm >> (i * 8 + j)) & 1u) {
        if (posn < KACT) {
          tk_idx[(size_t)b * KACT + posn] = tid * 8 + i * 4096 + j;
          tk_val[(size_t)b * KACT + posn] = vals[i * 8 + j];
        }
        ++posn;
      }
    }
}

// ---------------------------------------------------------------------------
// exact_patch: 192 threads = 3 waves; thread (c = t&63, p = t>>6) computes
// panel p of candidate c (sequential k-ascending fp32 chain, Kc=384 breaks —
// r3-proven np scheme); rank (val desc, idx asc); winners patch sparse row
// and fill tk slots [KACT-need, KACT).
// ---------------------------------------------------------------------------
__global__ __launch_bounds__(192) void exact_patch(const float* __restrict__ x,
                                                   const float* __restrict__ Wenc,
                                                   const int* __restrict__ cand_idx,
                                                   const float* __restrict__ cand_aval,
                                                   const int* __restrict__ row_cnt,
                                                   const int* __restrict__ row_need,
                                                   float* __restrict__ enc,
                                                   int* __restrict__ tk_idx,
                                                   float* __restrict__ tk_val) {
  const int b = blockIdx.x;
  const int t = threadIdx.x;
  __shared__ float xs[IN_DIM];
  for (int i = t; i < IN_DIM / 4; i += 192)
    *(f32x4*)(xs + i * 4) = *(const f32x4*)(x + (size_t)b * IN_DIM + i * 4);

  const int cnt = row_cnt[b];
  const int need = row_need[b];
  __shared__ int eidx[CCAP];
  __shared__ float eaval[CCAP];
  __shared__ float spp[CCAP][3];
  __shared__ float evals[CCAP];
  for (int c = t; c < cnt; c += 192) {
    eidx[c] = cand_idx[(size_t)b * CCAP + c];
    eaval[c] = cand_aval[(size_t)b * CCAP + c];
  }
  __syncthreads();

  const int p = t >> 6;            // panel 0..2
  const int lane = t & 63;
  const int k0 = p * 384;
  const int k1 = (p == 2) ? 1024 : (k0 + 384);

  for (int c = lane; c < cnt; c += 64) {
    const float* w = Wenc + (size_t)eidx[c] * IN_DIM;
    float acc = 0.f;
    for (int k = k0; k < k1; k += 16) {
      const f32x4 w0 = *(const f32x4*)(w + k);
      const f32x4 w1 = *(const f32x4*)(w + k + 4);
      const f32x4 w2 = *(const f32x4*)(w + k + 8);
      const f32x4 w3 = *(const f32x4*)(w + k + 12);
#pragma unroll
      for (int j = 0; j < 4; ++j) acc = fmaf(xs[k + j], w0[j], acc);
#pragma unroll
      for (int j = 0; j < 4; ++j) acc = fmaf(xs[k + 4 + j], w1[j], acc);
#pragma unroll
      for (int j = 0; j < 4; ++j) acc = fmaf(xs[k + 8 + j], w2[j], acc);
#pragma unroll
      for (int j = 0; j < 4; ++j) acc = fmaf(xs[k + 12 + j], w3[j], acc);
    }
    spp[c][p] = acc;
  }
  __syncthreads();
  if (t < cnt) evals[t] = (spp[t][0] + spp[t][1]) + spp[t][2];
  __syncthreads();

  if (t < cnt && need > 0) {
    const float e = evals[t];
    const int myidx = eidx[t];
    int rank = 0;
    for (int c = 0; c < cnt; ++c)
      rank += (evals[c] > e) || (evals[c] == e && eidx[c] < myidx);
    if (rank < need) {
      const float v = eaval[t];
      enc[(size_t)b * HID + myidx] = v;
      const int slot = (KACT - need) + rank;
      tk_idx[(size_t)b * KACT + slot] = myidx;
      tk_val[(size_t)b * KACT + slot] = v;
    }
  }
}

// ---------------------------------------------------------------------------
// decoder_t: decoded[b,:] = sum_k val_k * WdT_b[idx_k,:] (bf16 weights)
// ---------------------------------------------------------------------------
__global__ __launch_bounds__(256) void decoder_t(const int* __restrict__ tk_idx,
                                                 const float* __restrict__ tk_val,
                                                 const uint16_t* __restrict__ WdT_b,
                                                 float* __restrict__ out) {
  const int b = blockIdx.x;
  const int tid = threadIdx.x;
  __shared__ int sidx[KACT];
  __shared__ float sval[KACT];
  if (tid < KACT) {
    sidx[tid] = tk_idx[(size_t)b * KACT + tid];
    sval[tid] = tk_val[(size_t)b * KACT + tid];
  }
  __syncthreads();
  f32x4 acc = {0.f, 0.f, 0.f, 0.f};
  for (int k = 0; k < KACT; ++k) {
    const u16x4 w4 = *(const u16x4*)(WdT_b + (size_t)sidx[k] * IN_DIM + tid * 4);
    const float v = sval[k];
    acc[0] = fmaf(v, bf2f(w4[0]), acc[0]);
    acc[1] = fmaf(v, bf2f(w4[1]), acc[1]);
    acc[2] = fmaf(v, bf2f(w4[2]), acc[2]);
    acc[3] = fmaf(v, bf2f(w4[3]), acc[3]);
  }
  *(f32x4*)(out + (size_t)b * IN_DIM + tid * 4) = acc;
}

// ---------------------------------------------------------------------------
// W_dec [IN_DIM][HID] f32 -> W_decT [HID][IN_DIM] bf16
// ---------------------------------------------------------------------------
__global__ __launch_bounds__(256) void transpose_wdec(const float* __restrict__ Wd,
                                                      uint16_t* __restrict__ WdT_b) {
  __shared__ float t[32][33];
  const int tx = threadIdx.x & 31;
  const int ty = threadIdx.x >> 5;
  const int hb = blockIdx.x * 32;
  const int ib = blockIdx.y * 32;
#pragma unroll
  for (int r = ty; r < 32; r += 8)
    t[r][tx] = Wd[(size_t)(ib + r) * HID + hb + tx];
  __syncthreads();
  const int tx2 = threadIdx.x & 15;
  const int ty2 = threadIdx.x >> 4;
#pragma unroll
  for (int c = ty2; c < 32; c += 16) {
    uint32_t pk = (uint32_t)f2bf(t[2 * tx2][c]) |
                  ((uint32_t)f2bf(t[2 * tx2 + 1][c]) << 16);
    *(uint32_t*)(WdT_b + (size_t)(hb + c) * IN_DIM + ib + 2 * tx2) = pk;
  }
}

// ---------------------------------------------------------------------------
// Fallback (r3-proven): fp32 vector GEMM + radix topk + gather decoder
// ---------------------------------------------------------------------------
__global__ __launch_bounds__(256) void enc_gemm(const float* __restrict__ A,
                                                const float* __restrict__ Bw,
                                                float* __restrict__ C) {
  __shared__ float As[16][132];
  __shared__ float Bs[16][132];
  const int tid = threadIdx.x;
  const int bm = blockIdx.y;
  const int bn = blockIdx.x;
  const int m0 = (tid >> 4) << 3;
  const int n0 = (tid & 15) << 3;
  float tot[8][8] = {};
  float acc[8][8] = {};
  const float* Ablk = A + (size_t)bm * 128 * IN_DIM;
  const float* Bblk = Bw + (size_t)bn * 128 * IN_DIM;
  for (int k0 = 0; k0 < IN_DIM; k0 += 16) {
#pragma unroll
    for (int l = 0; l < 2; ++l) {
      int li = tid + l * 256;
      int row = li >> 2;
      int c4 = (li & 3) << 2;
      float4 va = *reinterpret_cast<const float4*>(Ablk + (size_t)row * IN_DIM + k0 + c4);
      As[c4 + 0][row] = va.x; As[c4 + 1][row] = va.y;
      As[c4 + 2][row] = va.z; As[c4 + 3][row] = va.w;
      float4 vb = *reinterpret_cast<const float4*>(Bblk + (size_t)row * IN_DIM + k0 + c4);
      Bs[c4 + 0][row] = vb.x; Bs[c4 + 1][row] = vb.y;
      Bs[c4 + 2][row] = vb.z; Bs[c4 + 3][row] = vb.w;
    }
    __syncthreads();
#pragma unroll
    for (int kk = 0; kk < 16; ++kk) {
      float a[8], b[8];
#pragma unroll
      for (int i = 0; i < 8; ++i) a[i] = As[kk][m0 + i];
#pragma unroll
      for (int j = 0; j < 8; ++j) b[j] = Bs[kk][n0 + j];
#pragma unroll
      for (int i = 0; i < 8; ++i)
#pragma unroll
        for (int j = 0; j < 8; ++j) acc[i][j] = fmaf(a[i], b[j], acc[i][j]);
    }
    __syncthreads();
    const int kend = k0 + 16;
    if (kend == 384 || kend == 768 || kend == IN_DIM) {
#pragma unroll
      for (int i = 0; i < 8; ++i)
#pragma unroll
        for (int j = 0; j < 8; ++j) { tot[i][j] += acc[i][j]; acc[i][j] = 0.0f; }
    }
  }
  float* Cblk = C + (size_t)(bm * 128) * HID + bn * 128;
#pragma unroll
  for (int i = 0; i < 8; ++i) {
    float4 v0 = make_float4(tot[i][0], tot[i][1], tot[i][2], tot[i][3]);
    float4 v1 = make_float4(tot[i][4], tot[i][5], tot[i][6], tot[i][7]);
    *reinterpret_cast<float4*>(Cblk + (size_t)(m0 + i) * HID + n0) = v0;
    *reinterpret_cast<float4*>(Cblk + (size_t)(m0 + i) * HID + n0 + 4) = v1;
  }
}

__global__ __launch_bounds__(256) void topk_kernel(float* __restrict__ enc,
                                                   int* __restrict__ tk_idx,
                                                   float* __restrict__ tk_val) {
  const int b = blockIdx.x;
  const int tid = threadIdx.x;
  float* row = enc + (size_t)b * HID;
  uint32_t keys[64];
#pragma unroll
  for (int i = 0; i < 64; ++i) keys[i] = fmap(row[tid + (i << 8)]);
  __shared__ uint32_t hist[256];
  __shared__ uint32_t sfx[256];
  __shared__ uint32_t s_prefix, s_krem;
  __shared__ int eqidx[256];
  __shared__ uint32_t eqcnt;
  if (tid == 0) { s_prefix = 0u; s_krem = KACT; }
  for (int pass = 0; pass < 4; ++pass) {
    const int shift = 24 - pass * 8;
    hist[tid] = 0;
    __syncthreads();
    const uint32_t pm = pass ? (0xFFFFFFFFu << (shift + 8)) : 0u;
    const uint32_t prefix = s_prefix;
#pragma unroll
    for (int i = 0; i < 64; ++i)
      if ((keys[i] & pm) == prefix) atomicAdd(&hist[(keys[i] >> shift) & 255], 1u);
    __syncthreads();
    sfx[tid] = hist[tid];
    __syncthreads();
    for (int d = 1; d < 256; d <<= 1) {
      uint32_t add = (tid + d < 256) ? sfx[tid + d] : 0u;
      __syncthreads();
      sfx[tid] += add;
      __syncthreads();
    }
    const uint32_t krem = s_krem;
    __syncthreads();
    const uint32_t above = sfx[tid] - hist[tid];
    if (above < krem && sfx[tid] >= krem) {
      s_prefix = prefix | ((uint32_t)tid << shift);
      s_krem = krem - above;
    }
    __syncthreads();
  }
  const uint32_t T = s_prefix;
  const uint32_t take_eq = s_krem;
  if (tid == 0) eqcnt = 0;
  __syncthreads();
#pragma unroll
  for (int i = 0; i < 64; ++i)
    if (keys[i] == T) {
      uint32_t p = atomicAdd(&eqcnt, 1u);
      if (p < 256u) eqidx[p] = tid + (i << 8);
    }
  __syncthreads();
  if (tid == 0) {
    int n = (int)min(eqcnt, 256u);
    for (int a = 1; a < n; ++a) {
      int v = eqidx[a]; int c = a - 1;
      while (c >= 0 && eqidx[c] > v) { eqidx[c + 1] = eqidx[c]; --c; }
      eqidx[c + 1] = v;
    }
  }
  __syncthreads();
  uint64_t keepm = 0ull;
  uint32_t cnt = 0;
#pragma unroll
  for (int i = 0; i < 64; ++i) {
    const int idx = tid + (i << 8);
    const uint32_t u = keys[i];
    bool keep = (u > T);
    if (u == T) {
      for (uint32_t e = 0; e < take_eq; ++e)
        if (eqidx[e] == idx) { keep = true; break; }
    }
    if (keep) { keepm |= (1ull << i); ++cnt; }
  }
  sfx[tid] = cnt;
  __syncthreads();
  for (int d = 1; d < 256; d <<= 1) {
    uint32_t add = (tid >= d) ? sfx[tid - d] : 0u;
    __syncthreads();
    sfx[tid] += add;
    __syncthreads();
  }
  uint32_t pos = sfx[tid] - cnt;
#pragma unroll
  for (int i = 0; i < 64; ++i) {
    const int idx = tid + (i << 8);
    const uint32_t u = keys[i];
    const uint32_t sbits = (u & 0x80000000u) ? (u ^ 0x80000000u) : ~u;
    const float f = __uint_as_float(sbits);
    const bool keep = (keepm >> i) & 1ull;
    row[idx] = keep ? f : 0.0f;
    if (keep) {
      tk_idx[(size_t)b * KACT + pos] = idx;
      tk_val[(size_t)b * KACT + pos] = f;
      ++pos;
    }
  }
}

__global__ __launch_bounds__(256) void decoder_g(const int* __restrict__ tk_idx,
                                                 const float* __restrict__ tk_val,
                                                 const float* __restrict__ Wd,
                                                 float* __restrict__ out) {
  const int b = blockIdx.x;
  const int tid = threadIdx.x;
  __shared__ int sidx[KACT];
  __shared__ float sval[KACT];
  if (tid < KACT) {
    sidx[tid] = tk_idx[(size_t)b * KACT + tid];
    sval[tid] = tk_val[(size_t)b * KACT + tid];
  }
  __syncthreads();
  float acc[4] = {0.f, 0.f, 0.f, 0.f};
  for (int k = 0; k < KACT; ++k) {
    const int h = sidx[k];
    const float v = sval[k];
#pragma unroll
    for (int j = 0; j < 4; ++j)
      acc[j] = fmaf(v, Wd[(size_t)(tid + j * 256) * HID + h], acc[j]);
  }
#pragma unroll
  for (int j = 0; j < 4; ++j) out[(size_t)b * IN_DIM + tid + j * 256] = acc[j];
}

// ---------------------------------------------------------------------------
extern "C" void kernel_launch(void* const* d_in, const int* in_sizes, int n_in,
                              void* d_out, int out_size, void* d_ws, size_t ws_size,
                              hipStream_t stream) {
  const float* x = (const float*)d_in[0];
  const float* Wenc = (const float*)d_in[1];
  const float* Wdec = (const float*)d_in[2];
  float* out = (float*)d_out;
  float* decoded = out;
  float* sparse = out + (size_t)BATCH * IN_DIM;

  const size_t MB = 1024ull * 1024ull;
  char* ws = (char*)d_ws;
  int*   tk_idx    = (int*)(ws + 0 * MB);
  float* tk_val    = (float*)(ws + 1 * MB);
  int*   cand_idx  = (int*)(ws + 2 * MB);
  float* cand_aval = (float*)(ws + 4 * MB);
  int*   row_cnt   = (int*)(ws + 6 * MB);
  int*   row_need  = (int*)(ws + 6 * MB + 65536);
  uint16_t* A2     = (uint16_t*)(ws + 8 * MB);
  uint16_t* B2     = (uint16_t*)(ws + 16 * MB);
  uint16_t* WdT_b  = (uint16_t*)(ws + 48 * MB);

  const size_t need_new = 80 * MB;

  if (ws_size >= need_new) {
    convert_bf16<<<1024, 256, 0, stream>>>(x, A2, (size_t)BATCH * IN_DIM / 4);
    convert_bf16<<<2048, 256, 0, stream>>>(Wenc, B2, (size_t)HID * IN_DIM / 4);
    mfma_gemm<<<4096, 256, 0, stream>>>(A2, B2, (uint16_t*)sparse);
    transpose_wdec<<<dim3(HID / 32, IN_DIM / 32), 256, 0, stream>>>(Wdec, WdT_b);
    select_bin<<<BATCH, 512, 0, stream>>>(sparse, tk_idx, tk_val, cand_idx,
                                          cand_aval, row_cnt, row_need);
    exact_patch<<<BATCH, 192, 0, stream>>>(x, Wenc, cand_idx, cand_aval,
                                           row_cnt, row_need, sparse,
                                           tk_idx, tk_val);
    decoder_t<<<BATCH, 256, 0, stream>>>(tk_idx, tk_val, WdT_b, decoded);
  } else {
    enc_gemm<<<dim3(HID / 128, BATCH / 128), 256, 0, stream>>>(x, Wenc, sparse);
    topk_kernel<<<BATCH, 256, 0, stream>>>(sparse, tk_idx, tk_val);
    decoder_g<<<BATCH, 256, 0, stream>>>(tk_idx, tk_val, Wdec, decoded);
  }
}

// Round 17
// 469.260 us; speedup vs baseline: 1.2203x; 1.0556x over previous
//
#include <hip/hip_runtime.h>
#include <stdint.h>

#define BATCH 4096
#define IN_DIM 1024
#define HID 16384
#define KACT 64
#define EPS2 0.06f   // margin; |bf16(v_mfma) - v_np| <= ~0.035 < EPS2
#define CCAP 128

typedef short bf16x8 __attribute__((ext_vector_type(8)));
typedef short short8 __attribute__((ext_vector_type(8)));
typedef unsigned short u16x4 __attribute__((ext_vector_type(4)));
typedef float f32x4 __attribute__((ext_vector_type(4)));

__device__ __forceinline__ uint16_t f2bf(float f) {
  uint32_t u = __float_as_uint(f);
  return (uint16_t)((u + 0x7FFFu + ((u >> 16) & 1u)) >> 16);
}
__device__ __forceinline__ float bf2f(uint16_t h) {
  return __uint_as_float((uint32_t)h << 16);
}
__device__ __forceinline__ uint32_t fmap(float f) {
  uint32_t u = __float_as_uint(f);
  return (u & 0x80000000u) ? ~u : (u | 0x80000000u);
}
__device__ __forceinline__ void gload_lds16(const void* g, void* l) {
  __builtin_amdgcn_global_load_lds(
      (const __attribute__((address_space(1))) unsigned int*)g,
      (__attribute__((address_space(3))) unsigned int*)l, 16, 0, 0);
}

// ---------------------------------------------------------------------------
// Plain bf16 cast: out[i] = bf16(in[i]), 4 elems/thread
// ---------------------------------------------------------------------------
__global__ __launch_bounds__(256) void convert_bf16(const float* __restrict__ in,
                                                    uint16_t* __restrict__ out,
                                                    size_t n4) {
  for (size_t i = (size_t)blockIdx.x * 256 + threadIdx.x; i < n4;
       i += (size_t)gridDim.x * 256) {
    f32x4 v = *(const f32x4*)(in + i * 4);
    uint64_t pk = (uint64_t)f2bf(v[0]) | ((uint64_t)f2bf(v[1]) << 16) |
                  ((uint64_t)f2bf(v[2]) << 32) | ((uint64_t)f2bf(v[3]) << 48);
    *(uint64_t*)(out + i * 4) = pk;
  }
}

// ---------------------------------------------------------------------------
// bf16 MFMA GEMM, 128x128 tile, BK=64, K=1024, XCD-grouped order.
// 2-phase double-buffered LDS; 16x16x32 MFMA (16-row reads -> 2-way LDS
// aliasing = free; 32x32 shape was a 4-way conflict — r16 lesson).
// Swapped operands -> packed 8B bf16 stores. s_setprio around MFMA (T5).
// ---------------------------------------------------------------------------
__global__ __launch_bounds__(256) void mfma_gemm(const uint16_t* __restrict__ A2,
                                                 const uint16_t* __restrict__ B2,
                                                 uint16_t* __restrict__ Cb) {
  __shared__ __attribute__((aligned(16))) char lds[2][32768];
  const int tid = threadIdx.x;
  const int lane = tid & 63;
  const int wave = tid >> 6;
  const int wr = wave >> 1, wc = wave & 1;

  const int bid = blockIdx.x;
  const int xcd = bid & 7;
  const int pos = bid >> 3;
  const int g = pos >> 4;
  const int rem = pos & 15;
  const int bm = xcd * 4 + (rem >> 2);
  const int bn = g * 4 + (rem & 3);

  const char* Abase = (const char*)(A2 + (size_t)(bm * 128) * IN_DIM);
  const char* Bbase = (const char*)(B2 + (size_t)(bn * 128) * IN_DIM);

  const int srow = lane >> 3;
  const int scolb = (lane & 7) << 4;

  auto stage = [&](int kt, int buf) {
    const int colB = kt * 128;
#pragma unroll
    for (int j = 0; j < 4; ++j) {
      const int r0 = wave * 32 + j * 8;
      const int row = r0 + srow;
      const int swz = (row & 7) << 4;
      gload_lds16(Abase + (size_t)row * 2048 + colB + (scolb ^ swz),
                  lds[buf] + r0 * 128);
      gload_lds16(Bbase + (size_t)row * 2048 + colB + (scolb ^ swz),
                  lds[buf] + 16384 + r0 * 128);
    }
  };

  f32x4 acc[4][4] = {};

  stage(0, 0);
  __syncthreads();

  for (int kt = 0; kt < 16; ++kt) {
    const int buf = kt & 1;
    if (kt < 15) stage(kt + 1, buf ^ 1);

#pragma unroll
    for (int ku = 0; ku < 2; ++ku) {
      bf16x8 af[4], bf_[4];
      const int kb = ku * 64 + ((lane >> 4) << 4);
#pragma unroll
      for (int m = 0; m < 4; ++m) {
        const int row = wr * 64 + m * 16 + (lane & 15);
        af[m] = *(const bf16x8*)(lds[buf] + row * 128 + (kb ^ ((row & 7) << 4)));
      }
#pragma unroll
      for (int n = 0; n < 4; ++n) {
        const int row = wc * 64 + n * 16 + (lane & 15);
        bf_[n] = *(const bf16x8*)(lds[buf] + 16384 + row * 128 +
                                  (kb ^ ((row & 7) << 4)));
      }
      __builtin_amdgcn_s_setprio(1);
#pragma unroll
      for (int m = 0; m < 4; ++m)
#pragma unroll
        for (int n = 0; n < 4; ++n)
          acc[m][n] = __builtin_amdgcn_mfma_f32_16x16x32_bf16(bf_[n], af[m],
                                                              acc[m][n], 0, 0, 0);
      __builtin_amdgcn_s_setprio(0);
    }
    __syncthreads();
  }

#pragma unroll
  for (int m = 0; m < 4; ++m) {
    const int grow = bm * 128 + wr * 64 + m * 16 + (lane & 15);
    uint16_t* rowp = Cb + (size_t)grow * (2 * HID);
#pragma unroll
    for (int n = 0; n < 4; ++n) {
      const int gcol0 = bn * 128 + wc * 64 + n * 16 + ((lane >> 4) << 2);
      uint2 pk;
      pk.x = (uint32_t)f2bf(acc[m][n][0]) | ((uint32_t)f2bf(acc[m][n][1]) << 16);
      pk.y = (uint32_t)f2bf(acc[m][n][2]) | ((uint32_t)f2bf(acc[m][n][3]) << 16);
      *(uint2*)(rowp + gcol0) = pk;
    }
  }
}

// ---------------------------------------------------------------------------
// select_bin (512 threads, 32 vals/thread): reads bf16 C, binary-search
// threshold bracket (11 iters), classifies sure/window, writes full f32
// sparse row, emits compact sure list + window candidates + per-row meta.
// ---------------------------------------------------------------------------
__global__ __launch_bounds__(512) void select_bin(float* __restrict__ enc,
                                                  int* __restrict__ tk_idx,
                                                  float* __restrict__ tk_val,
                                                  int* __restrict__ cand_idx,
                                                  float* __restrict__ cand_aval,
                                                  int* __restrict__ row_cnt,
                                                  int* __restrict__ row_need) {
  const int b = blockIdx.x;
  const int tid = threadIdx.x;        // 0..511
  const int lane = tid & 63;
  const int wid = tid >> 6;           // 0..7
  float* rowf = enc + (size_t)b * HID;
  const uint16_t* rb = (const uint16_t*)rowf;

  float vals[32];
#pragma unroll
  for (int i = 0; i < 4; ++i) {
    short8 v8 = *(const short8*)(rb + tid * 8 + i * 4096);
#pragma unroll
    for (int j = 0; j < 8; ++j) vals[i * 8 + j] = bf2f((uint16_t)v8[j]);
  }

  // ---- binary search bracket: count(v > hi) < 64 <= count(v > lo) ----
  __shared__ uint32_t wsum[2][8];
  float lo = -16.0f, hi = 16.0f;
  for (int it = 0; it < 11; ++it) {
    const float mid = 0.5f * (lo + hi);
    uint32_t c = 0;
#pragma unroll
    for (int q = 0; q < 32; ++q) c += (vals[q] > mid);
#pragma unroll
    for (int d = 1; d < 64; d <<= 1) c += __shfl_xor(c, d, 64);
    if (lane == 0) wsum[it & 1][wid] = c;
    __syncthreads();
    uint32_t tot = 0;
#pragma unroll
    for (int w = 0; w < 8; ++w) tot += wsum[it & 1][w];
    if (tot >= (uint32_t)KACT) lo = mid; else hi = mid;
  }

  const float sure_thr = hi + EPS2;
  const float cand_lo = lo - EPS2;

  // ---- classify ----
  __shared__ uint32_t bitmap[HID / 32];   // 512 words, 1 per thread
  __shared__ uint32_t s_nc, s_cs;
  bitmap[tid] = 0u;
  if (tid == 0) { s_nc = 0u; s_cs = 0u; }
  __syncthreads();

  uint32_t cs = 0;
#pragma unroll
  for (int i = 0; i < 4; ++i)
#pragma unroll
    for (int j = 0; j < 8; ++j) {
      const float v = vals[i * 8 + j];
      const int idx = tid * 8 + i * 4096 + j;
      if (v > sure_thr) {
        ++cs;
        atomicOr(&bitmap[idx >> 5], 1u << (idx & 31));
      } else if (v >= cand_lo) {
        uint32_t p = atomicAdd(&s_nc, 1u);
        if (p < CCAP) {
          cand_idx[(size_t)b * CCAP + p] = idx;
          cand_aval[(size_t)b * CCAP + p] = v;
        }
      }
    }
#pragma unroll
  for (int d = 1; d < 64; d <<= 1) cs += __shfl_xor(cs, d, 64);
  if (lane == 0) atomicAdd(&s_cs, cs);
  __syncthreads();

  if (tid == 0) {
    row_cnt[b] = (int)min(s_nc, (uint32_t)CCAP);
    row_need[b] = KACT - (int)s_cs;   // >= 1 by bracket invariant
  }

  // ---- write full f32 sparse row + compact sure list ----
  uint32_t keepm = 0u;
  uint32_t c2 = 0;
#pragma unroll
  for (int i = 0; i < 4; ++i) {
    f32x4 o0, o1;
#pragma unroll
    for (int j = 0; j < 8; ++j) {
      const int idx = tid * 8 + i * 4096 + j;
      const float v = vals[i * 8 + j];
      const bool keep = (bitmap[idx >> 5] >> (idx & 31)) & 1u;
      const float ov = keep ? v : 0.0f;
      if (j < 4) o0[j] = ov; else o1[j - 4] = ov;
      if (keep) { keepm |= (1u << (i * 8 + j)); ++c2; }
    }
    *(f32x4*)(rowf + tid * 8 + i * 4096) = o0;
    *(f32x4*)(rowf + tid * 8 + i * 4096 + 4) = o1;
  }
  __shared__ uint32_t psum[8];
  uint32_t p = c2;
#pragma unroll
  for (int d = 1; d < 64; d <<= 1) {
    uint32_t o = __shfl_up(p, d, 64);
    if (lane >= d) p += o;
  }
  if (lane == 63) psum[wid] = p;
  __syncthreads();
  uint32_t off = 0;
  for (int w = 0; w < wid; ++w) off += psum[w];
  uint32_t posn = off + p - c2;
#pragma unroll
  for (int i = 0; i < 4; ++i)
#pragma unroll
    for (int j = 0; j < 8; ++j) {
      if ((keepm >> (i * 8 + j)) & 1u) {
        if (posn < KACT) {
          tk_idx[(size_t)b * KACT + posn] = tid * 8 + i * 4096 + j;
          tk_val[(size_t)b * KACT + posn] = vals[i * 8 + j];
        }
        ++posn;
      }
    }
}

// ---------------------------------------------------------------------------
// exact_patch: 192 threads = 3 waves; thread (c = t&63, p = t>>6) computes
// panel p of candidate c (sequential k-ascending fp32 chain, Kc=384 breaks —
// r3-proven np scheme); rank (val desc, idx asc); winners patch sparse row
// and fill tk slots [KACT-need, KACT).
// ---------------------------------------------------------------------------
__global__ __launch_bounds__(192) void exact_patch(const float* __restrict__ x,
                                                   const float* __restrict__ Wenc,
                                                   const int* __restrict__ cand_idx,
                                                   const float* __restrict__ cand_aval,
                                                   const int* __restrict__ row_cnt,
                                                   const int* __restrict__ row_need,
                                                   float* __restrict__ enc,
                                                   int* __restrict__ tk_idx,
                                                   float* __restrict__ tk_val) {
  const int b = blockIdx.x;
  const int t = threadIdx.x;
  __shared__ float xs[IN_DIM];
  for (int i = t; i < IN_DIM / 4; i += 192)
    *(f32x4*)(xs + i * 4) = *(const f32x4*)(x + (size_t)b * IN_DIM + i * 4);

  const int cnt = row_cnt[b];
  const int need = row_need[b];
  __shared__ int eidx[CCAP];
  __shared__ float eaval[CCAP];
  __shared__ float spp[CCAP][3];
  __shared__ float evals[CCAP];
  for (int c = t; c < cnt; c += 192) {
    eidx[c] = cand_idx[(size_t)b * CCAP + c];
    eaval[c] = cand_aval[(size_t)b * CCAP + c];
  }
  __syncthreads();

  const int p = t >> 6;            // panel 0..2
  const int lane = t & 63;
  const int k0 = p * 384;
  const int k1 = (p == 2) ? 1024 : (k0 + 384);

  for (int c = lane; c < cnt; c += 64) {
    const float* w = Wenc + (size_t)eidx[c] * IN_DIM;
    float acc = 0.f;
    for (int k = k0; k < k1; k += 16) {
      const f32x4 w0 = *(const f32x4*)(w + k);
      const f32x4 w1 = *(const f32x4*)(w + k + 4);
      const f32x4 w2 = *(const f32x4*)(w + k + 8);
      const f32x4 w3 = *(const f32x4*)(w + k + 12);
#pragma unroll
      for (int j = 0; j < 4; ++j) acc = fmaf(xs[k + j], w0[j], acc);
#pragma unroll
      for (int j = 0; j < 4; ++j) acc = fmaf(xs[k + 4 + j], w1[j], acc);
#pragma unroll
      for (int j = 0; j < 4; ++j) acc = fmaf(xs[k + 8 + j], w2[j], acc);
#pragma unroll
      for (int j = 0; j < 4; ++j) acc = fmaf(xs[k + 12 + j], w3[j], acc);
    }
    spp[c][p] = acc;
  }
  __syncthreads();
  if (t < cnt) evals[t] = (spp[t][0] + spp[t][1]) + spp[t][2];
  __syncthreads();

  if (t < cnt && need > 0) {
    const float e = evals[t];
    const int myidx = eidx[t];
    int rank = 0;
    for (int c = 0; c < cnt; ++c)
      rank += (evals[c] > e) || (evals[c] == e && eidx[c] < myidx);
    if (rank < need) {
      const float v = eaval[t];
      enc[(size_t)b * HID + myidx] = v;
      const int slot = (KACT - need) + rank;
      tk_idx[(size_t)b * KACT + slot] = myidx;
      tk_val[(size_t)b * KACT + slot] = v;
    }
  }
}

// ---------------------------------------------------------------------------
// decoder_t: decoded[b,:] = sum_k val_k * WdT_b[idx_k,:] (bf16 weights)
// ---------------------------------------------------------------------------
__global__ __launch_bounds__(256) void decoder_t(const int* __restrict__ tk_idx,
                                                 const float* __restrict__ tk_val,
                                                 const uint16_t* __restrict__ WdT_b,
                                                 float* __restrict__ out) {
  const int b = blockIdx.x;
  const int tid = threadIdx.x;
  __shared__ int sidx[KACT];
  __shared__ float sval[KACT];
  if (tid < KACT) {
    sidx[tid] = tk_idx[(size_t)b * KACT + tid];
    sval[tid] = tk_val[(size_t)b * KACT + tid];
  }
  __syncthreads();
  f32x4 acc = {0.f, 0.f, 0.f, 0.f};
  for (int k = 0; k < KACT; ++k) {
    const u16x4 w4 = *(const u16x4*)(WdT_b + (size_t)sidx[k] * IN_DIM + tid * 4);
    const float v = sval[k];
    acc[0] = fmaf(v, bf2f(w4[0]), acc[0]);
    acc[1] = fmaf(v, bf2f(w4[1]), acc[1]);
    acc[2] = fmaf(v, bf2f(w4[2]), acc[2]);
    acc[3] = fmaf(v, bf2f(w4[3]), acc[3]);
  }
  *(f32x4*)(out + (size_t)b * IN_DIM + tid * 4) = acc;
}

// ---------------------------------------------------------------------------
// W_dec [IN_DIM][HID] f32 -> W_decT [HID][IN_DIM] bf16
// ---------------------------------------------------------------------------
__global__ __launch_bounds__(256) void transpose_wdec(const float* __restrict__ Wd,
                                                      uint16_t* __restrict__ WdT_b) {
  __shared__ float t[32][33];
  const int tx = threadIdx.x & 31;
  const int ty = threadIdx.x >> 5;
  const int hb = blockIdx.x * 32;
  const int ib = blockIdx.y * 32;
#pragma unroll
  for (int r = ty; r < 32; r += 8)
    t[r][tx] = Wd[(size_t)(ib + r) * HID + hb + tx];
  __syncthreads();
  const int tx2 = threadIdx.x & 15;
  const int ty2 = threadIdx.x >> 4;
#pragma unroll
  for (int c = ty2; c < 32; c += 16) {
    uint32_t pk = (uint32_t)f2bf(t[2 * tx2][c]) |
                  ((uint32_t)f2bf(t[2 * tx2 + 1][c]) << 16);
    *(uint32_t*)(WdT_b + (size_t)(hb + c) * IN_DIM + ib + 2 * tx2) = pk;
  }
}

// ---------------------------------------------------------------------------
// Fallback (r3-proven): fp32 vector GEMM + radix topk + gather decoder
// ---------------------------------------------------------------------------
__global__ __launch_bounds__(256) void enc_gemm(const float* __restrict__ A,
                                                const float* __restrict__ Bw,
                                                float* __restrict__ C) {
  __shared__ float As[16][132];
  __shared__ float Bs[16][132];
  const int tid = threadIdx.x;
  const int bm = blockIdx.y;
  const int bn = blockIdx.x;
  const int m0 = (tid >> 4) << 3;
  const int n0 = (tid & 15) << 3;
  float tot[8][8] = {};
  float acc[8][8] = {};
  const float* Ablk = A + (size_t)bm * 128 * IN_DIM;
  const float* Bblk = Bw + (size_t)bn * 128 * IN_DIM;
  for (int k0 = 0; k0 < IN_DIM; k0 += 16) {
#pragma unroll
    for (int l = 0; l < 2; ++l) {
      int li = tid + l * 256;
      int row = li >> 2;
      int c4 = (li & 3) << 2;
      float4 va = *reinterpret_cast<const float4*>(Ablk + (size_t)row * IN_DIM + k0 + c4);
      As[c4 + 0][row] = va.x; As[c4 + 1][row] = va.y;
      As[c4 + 2][row] = va.z; As[c4 + 3][row] = va.w;
      float4 vb = *reinterpret_cast<const float4*>(Bblk + (size_t)row * IN_DIM + k0 + c4);
      Bs[c4 + 0][row] = vb.x; Bs[c4 + 1][row] = vb.y;
      Bs[c4 + 2][row] = vb.z; Bs[c4 + 3][row] = vb.w;
    }
    __syncthreads();
#pragma unroll
    for (int kk = 0; kk < 16; ++kk) {
      float a[8], b[8];
#pragma unroll
      for (int i = 0; i < 8; ++i) a[i] = As[kk][m0 + i];
#pragma unroll
      for (int j = 0; j < 8; ++j) b[j] = Bs[kk][n0 + j];
#pragma unroll
      for (int i = 0; i < 8; ++i)
#pragma unroll
        for (int j = 0; j < 8; ++j) acc[i][j] = fmaf(a[i], b[j], acc[i][j]);
    }
    __syncthreads();
    const int kend = k0 + 16;
    if (kend == 384 || kend == 768 || kend == IN_DIM) {
#pragma unroll
      for (int i = 0; i < 8; ++i)
#pragma unroll
        for (int j = 0; j < 8; ++j) { tot[i][j] += acc[i][j]; acc[i][j] = 0.0f; }
    }
  }
  float* Cblk = C + (size_t)(bm * 128) * HID + bn * 128;
#pragma unroll
  for (int i = 0; i < 8; ++i) {
    float4 v0 = make_float4(tot[i][0], tot[i][1], tot[i][2], tot[i][3]);
    float4 v1 = make_float4(tot[i][4], tot[i][5], tot[i][6], tot[i][7]);
    *reinterpret_cast<float4*>(Cblk + (size_t)(m0 + i) * HID + n0) = v0;
    *reinterpret_cast<float4*>(Cblk + (size_t)(m0 + i) * HID + n0 + 4) = v1;
  }
}

__global__ __launch_bounds__(256) void topk_kernel(float* __restrict__ enc,
                                                   int* __restrict__ tk_idx,
                                                   float* __restrict__ tk_val) {
  const int b = blockIdx.x;
  const int tid = threadIdx.x;
  float* row = enc + (size_t)b * HID;
  uint32_t keys[64];
#pragma unroll
  for (int i = 0; i < 64; ++i) keys[i] = fmap(row[tid + (i << 8)]);
  __shared__ uint32_t hist[256];
  __shared__ uint32_t sfx[256];
  __shared__ uint32_t s_prefix, s_krem;
  __shared__ int eqidx[256];
  __shared__ uint32_t eqcnt;
  if (tid == 0) { s_prefix = 0u; s_krem = KACT; }
  for (int pass = 0; pass < 4; ++pass) {
    const int shift = 24 - pass * 8;
    hist[tid] = 0;
    __syncthreads();
    const uint32_t pm = pass ? (0xFFFFFFFFu << (shift + 8)) : 0u;
    const uint32_t prefix = s_prefix;
#pragma unroll
    for (int i = 0; i < 64; ++i)
      if ((keys[i] & pm) == prefix) atomicAdd(&hist[(keys[i] >> shift) & 255], 1u);
    __syncthreads();
    sfx[tid] = hist[tid];
    __syncthreads();
    for (int d = 1; d < 256; d <<= 1) {
      uint32_t add = (tid + d < 256) ? sfx[tid + d] : 0u;
      __syncthreads();
      sfx[tid] += add;
      __syncthreads();
    }
    const uint32_t krem = s_krem;
    __syncthreads();
    const uint32_t above = sfx[tid] - hist[tid];
    if (above < krem && sfx[tid] >= krem) {
      s_prefix = prefix | ((uint32_t)tid << shift);
      s_krem = krem - above;
    }
    __syncthreads();
  }
  const uint32_t T = s_prefix;
  const uint32_t take_eq = s_krem;
  if (tid == 0) eqcnt = 0;
  __syncthreads();
#pragma unroll
  for (int i = 0; i < 64; ++i)
    if (keys[i] == T) {
      uint32_t p = atomicAdd(&eqcnt, 1u);
      if (p < 256u) eqidx[p] = tid + (i << 8);
    }
  __syncthreads();
  if (tid == 0) {
    int n = (int)min(eqcnt, 256u);
    for (int a = 1; a < n; ++a) {
      int v = eqidx[a]; int c = a - 1;
      while (c >= 0 && eqidx[c] > v) { eqidx[c + 1] = eqidx[c]; --c; }
      eqidx[c + 1] = v;
    }
  }
  __syncthreads();
  uint64_t keepm = 0ull;
  uint32_t cnt = 0;
#pragma unroll
  for (int i = 0; i < 64; ++i) {
    const int idx = tid + (i << 8);
    const uint32_t u = keys[i];
    bool keep = (u > T);
    if (u == T) {
      for (uint32_t e = 0; e < take_eq; ++e)
        if (eqidx[e] == idx) { keep = true; break; }
    }
    if (keep) { keepm |= (1ull << i); ++cnt; }
  }
  sfx[tid] = cnt;
  __syncthreads();
  for (int d = 1; d < 256; d <<= 1) {
    uint32_t add = (tid >= d) ? sfx[tid - d] : 0u;
    __syncthreads();
    sfx[tid] += add;
    __syncthreads();
  }
  uint32_t pos = sfx[tid] - cnt;
#pragma unroll
  for (int i = 0; i < 64; ++i) {
    const int idx = tid + (i << 8);
    const uint32_t u = keys[i];
    const uint32_t sbits = (u & 0x80000000u) ? (u ^ 0x80000000u) : ~u;
    const float f = __uint_as_float(sbits);
    const bool keep = (keepm >> i) & 1ull;
    row[idx] = keep ? f : 0.0f;
    if (keep) {
      tk_idx[(size_t)b * KACT + pos] = idx;
      tk_val[(size_t)b * KACT + pos] = f;
      ++pos;
    }
  }
}

__global__ __launch_bounds__(256) void decoder_g(const int* __restrict__ tk_idx,
                                                 const float* __restrict__ tk_val,
                                                 const float* __restrict__ Wd,
                                                 float* __restrict__ out) {
  const int b = blockIdx.x;
  const int tid = threadIdx.x;
  __shared__ int sidx[KACT];
  __shared__ float sval[KACT];
  if (tid < KACT) {
    sidx[tid] = tk_idx[(size_t)b * KACT + tid];
    sval[tid] = tk_val[(size_t)b * KACT + tid];
  }
  __syncthreads();
  float acc[4] = {0.f, 0.f, 0.f, 0.f};
  for (int k = 0; k < KACT; ++k) {
    const int h = sidx[k];
    const float v = sval[k];
#pragma unroll
    for (int j = 0; j < 4; ++j)
      acc[j] = fmaf(v, Wd[(size_t)(tid + j * 256) * HID + h], acc[j]);
  }
#pragma unroll
  for (int j = 0; j < 4; ++j) out[(size_t)b * IN_DIM + tid + j * 256] = acc[j];
}

// ---------------------------------------------------------------------------
extern "C" void kernel_launch(void* const* d_in, const int* in_sizes, int n_in,
                              void* d_out, int out_size, void* d_ws, size_t ws_size,
                              hipStream_t stream) {
  const float* x = (const float*)d_in[0];
  const float* Wenc = (const float*)d_in[1];
  const float* Wdec = (const float*)d_in[2];
  float* out = (float*)d_out;
  float* decoded = out;
  float* sparse = out + (size_t)BATCH * IN_DIM;

  const size_t MB = 1024ull * 1024ull;
  char* ws = (char*)d_ws;
  int*   tk_idx    = (int*)(ws + 0 * MB);
  float* tk_val    = (float*)(ws + 1 * MB);
  int*   cand_idx  = (int*)(ws + 2 * MB);
  float* cand_aval = (float*)(ws + 4 * MB);
  int*   row_cnt   = (int*)(ws + 6 * MB);
  int*   row_need  = (int*)(ws + 6 * MB + 65536);
  uint16_t* A2     = (uint16_t*)(ws + 8 * MB);
  uint16_t* B2     = (uint16_t*)(ws + 16 * MB);
  uint16_t* WdT_b  = (uint16_t*)(ws + 48 * MB);

  const size_t need_new = 80 * MB;

  if (ws_size >= need_new) {
    convert_bf16<<<1024, 256, 0, stream>>>(x, A2, (size_t)BATCH * IN_DIM / 4);
    convert_bf16<<<2048, 256, 0, stream>>>(Wenc, B2, (size_t)HID * IN_DIM / 4);
    mfma_gemm<<<4096, 256, 0, stream>>>(A2, B2, (uint16_t*)sparse);
    transpose_wdec<<<dim3(HID / 32, IN_DIM / 32), 256, 0, stream>>>(Wdec, WdT_b);
    select_bin<<<BATCH, 512, 0, stream>>>(sparse, tk_idx, tk_val, cand_idx,
                                          cand_aval, row_cnt, row_need);
    exact_patch<<<BATCH, 192, 0, stream>>>(x, Wenc, cand_idx, cand_aval,
                                           row_cnt, row_need, sparse,
                                           tk_idx, tk_val);
    decoder_t<<<BATCH, 256, 0, stream>>>(tk_idx, tk_val, WdT_b, decoded);
  } else {
    enc_gemm<<<dim3(HID / 128, BATCH / 128), 256, 0, stream>>>(x, Wenc, sparse);
    topk_kernel<<<BATCH, 256, 0, stream>>>(sparse, tk_idx, tk_val);
    decoder_g<<<BATCH, 256, 0, stream>>>(tk_idx, tk_val, Wdec, decoded);
  }
}

// Round 18
// 457.889 us; speedup vs baseline: 1.2507x; 1.0248x over previous
//
#include <hip/hip_runtime.h>
#include <stdint.h>

#define BATCH 4096
#define IN_DIM 1024
#define HID 16384
#define KACT 64
#define EPS2 0.06f   // margin; |bf16(v_mfma) - v_np| <= ~0.035 < EPS2
#define CCAP 128

typedef short bf16x8 __attribute__((ext_vector_type(8)));
typedef short short8 __attribute__((ext_vector_type(8)));
typedef unsigned short u16x4 __attribute__((ext_vector_type(4)));
typedef float f32x4 __attribute__((ext_vector_type(4)));

__device__ __forceinline__ uint16_t f2bf(float f) {
  uint32_t u = __float_as_uint(f);
  return (uint16_t)((u + 0x7FFFu + ((u >> 16) & 1u)) >> 16);
}
__device__ __forceinline__ float bf2f(uint16_t h) {
  return __uint_as_float((uint32_t)h << 16);
}
__device__ __forceinline__ uint32_t fmap(float f) {
  uint32_t u = __float_as_uint(f);
  return (u & 0x80000000u) ? ~u : (u | 0x80000000u);
}
__device__ __forceinline__ void gload_lds16(const void* g, void* l) {
  __builtin_amdgcn_global_load_lds(
      (const __attribute__((address_space(1))) unsigned int*)g,
      (__attribute__((address_space(3))) unsigned int*)l, 16, 0, 0);
}

// ---------------------------------------------------------------------------
// convert_both: bf16 cast of x -> A2 and Wenc -> B2 in one launch
// ---------------------------------------------------------------------------
__global__ __launch_bounds__(256) void convert_both(const float* __restrict__ x,
                                                    const float* __restrict__ Wenc,
                                                    uint16_t* __restrict__ A2,
                                                    uint16_t* __restrict__ B2) {
  const size_t nx4 = (size_t)BATCH * IN_DIM / 4;
  const size_t nw4 = (size_t)HID * IN_DIM / 4;
  for (size_t i = (size_t)blockIdx.x * 256 + threadIdx.x; i < nx4;
       i += (size_t)gridDim.x * 256) {
    f32x4 v = *(const f32x4*)(x + i * 4);
    uint64_t pk = (uint64_t)f2bf(v[0]) | ((uint64_t)f2bf(v[1]) << 16) |
                  ((uint64_t)f2bf(v[2]) << 32) | ((uint64_t)f2bf(v[3]) << 48);
    *(uint64_t*)(A2 + i * 4) = pk;
  }
  for (size_t i = (size_t)blockIdx.x * 256 + threadIdx.x; i < nw4;
       i += (size_t)gridDim.x * 256) {
    f32x4 v = *(const f32x4*)(Wenc + i * 4);
    uint64_t pk = (uint64_t)f2bf(v[0]) | ((uint64_t)f2bf(v[1]) << 16) |
                  ((uint64_t)f2bf(v[2]) << 32) | ((uint64_t)f2bf(v[3]) << 48);
    *(uint64_t*)(B2 + i * 4) = pk;
  }
}

// ---------------------------------------------------------------------------
// bf16 MFMA GEMM, 128x128 tile, BK=64, K=1024, XCD-grouped order.
// 2-phase double-buffered LDS; 16x16x32 MFMA (16-row reads -> 2-way LDS
// aliasing = free; 32x32 shape was a 4-way conflict — r16 lesson).
// Swapped operands -> packed 8B bf16 stores. s_setprio around MFMA (T5).
// (r17-identical; at the 2-barrier-structure ceiling)
// ---------------------------------------------------------------------------
__global__ __launch_bounds__(256) void mfma_gemm(const uint16_t* __restrict__ A2,
                                                 const uint16_t* __restrict__ B2,
                                                 uint16_t* __restrict__ Cb) {
  __shared__ __attribute__((aligned(16))) char lds[2][32768];
  const int tid = threadIdx.x;
  const int lane = tid & 63;
  const int wave = tid >> 6;
  const int wr = wave >> 1, wc = wave & 1;

  const int bid = blockIdx.x;
  const int xcd = bid & 7;
  const int pos = bid >> 3;
  const int g = pos >> 4;
  const int rem = pos & 15;
  const int bm = xcd * 4 + (rem >> 2);
  const int bn = g * 4 + (rem & 3);

  const char* Abase = (const char*)(A2 + (size_t)(bm * 128) * IN_DIM);
  const char* Bbase = (const char*)(B2 + (size_t)(bn * 128) * IN_DIM);

  const int srow = lane >> 3;
  const int scolb = (lane & 7) << 4;

  auto stage = [&](int kt, int buf) {
    const int colB = kt * 128;
#pragma unroll
    for (int j = 0; j < 4; ++j) {
      const int r0 = wave * 32 + j * 8;
      const int row = r0 + srow;
      const int swz = (row & 7) << 4;
      gload_lds16(Abase + (size_t)row * 2048 + colB + (scolb ^ swz),
                  lds[buf] + r0 * 128);
      gload_lds16(Bbase + (size_t)row * 2048 + colB + (scolb ^ swz),
                  lds[buf] + 16384 + r0 * 128);
    }
  };

  f32x4 acc[4][4] = {};

  stage(0, 0);
  __syncthreads();

  for (int kt = 0; kt < 16; ++kt) {
    const int buf = kt & 1;
    if (kt < 15) stage(kt + 1, buf ^ 1);

#pragma unroll
    for (int ku = 0; ku < 2; ++ku) {
      bf16x8 af[4], bf_[4];
      const int kb = ku * 64 + ((lane >> 4) << 4);
#pragma unroll
      for (int m = 0; m < 4; ++m) {
        const int row = wr * 64 + m * 16 + (lane & 15);
        af[m] = *(const bf16x8*)(lds[buf] + row * 128 + (kb ^ ((row & 7) << 4)));
      }
#pragma unroll
      for (int n = 0; n < 4; ++n) {
        const int row = wc * 64 + n * 16 + (lane & 15);
        bf_[n] = *(const bf16x8*)(lds[buf] + 16384 + row * 128 +
                                  (kb ^ ((row & 7) << 4)));
      }
      __builtin_amdgcn_s_setprio(1);
#pragma unroll
      for (int m = 0; m < 4; ++m)
#pragma unroll
        for (int n = 0; n < 4; ++n)
          acc[m][n] = __builtin_amdgcn_mfma_f32_16x16x32_bf16(bf_[n], af[m],
                                                              acc[m][n], 0, 0, 0);
      __builtin_amdgcn_s_setprio(0);
    }
    __syncthreads();
  }

#pragma unroll
  for (int m = 0; m < 4; ++m) {
    const int grow = bm * 128 + wr * 64 + m * 16 + (lane & 15);
    uint16_t* rowp = Cb + (size_t)grow * (2 * HID);
#pragma unroll
    for (int n = 0; n < 4; ++n) {
      const int gcol0 = bn * 128 + wc * 64 + n * 16 + ((lane >> 4) << 2);
      uint2 pk;
      pk.x = (uint32_t)f2bf(acc[m][n][0]) | ((uint32_t)f2bf(acc[m][n][1]) << 16);
      pk.y = (uint32_t)f2bf(acc[m][n][2]) | ((uint32_t)f2bf(acc[m][n][3]) << 16);
      *(uint2*)(rowp + gcol0) = pk;
    }
  }
}

// ---------------------------------------------------------------------------
// select_bin (512 threads, 32 vals/thread): r17-identical.
// ---------------------------------------------------------------------------
__global__ __launch_bounds__(512) void select_bin(float* __restrict__ enc,
                                                  int* __restrict__ tk_idx,
                                                  float* __restrict__ tk_val,
                                                  int* __restrict__ cand_idx,
                                                  float* __restrict__ cand_aval,
                                                  int* __restrict__ row_cnt,
                                                  int* __restrict__ row_need) {
  const int b = blockIdx.x;
  const int tid = threadIdx.x;        // 0..511
  const int lane = tid & 63;
  const int wid = tid >> 6;           // 0..7
  float* rowf = enc + (size_t)b * HID;
  const uint16_t* rb = (const uint16_t*)rowf;

  float vals[32];
#pragma unroll
  for (int i = 0; i < 4; ++i) {
    short8 v8 = *(const short8*)(rb + tid * 8 + i * 4096);
#pragma unroll
    for (int j = 0; j < 8; ++j) vals[i * 8 + j] = bf2f((uint16_t)v8[j]);
  }

  __shared__ uint32_t wsum[2][8];
  float lo = -16.0f, hi = 16.0f;
  for (int it = 0; it < 11; ++it) {
    const float mid = 0.5f * (lo + hi);
    uint32_t c = 0;
#pragma unroll
    for (int q = 0; q < 32; ++q) c += (vals[q] > mid);
#pragma unroll
    for (int d = 1; d < 64; d <<= 1) c += __shfl_xor(c, d, 64);
    if (lane == 0) wsum[it & 1][wid] = c;
    __syncthreads();
    uint32_t tot = 0;
#pragma unroll
    for (int w = 0; w < 8; ++w) tot += wsum[it & 1][w];
    if (tot >= (uint32_t)KACT) lo = mid; else hi = mid;
  }

  const float sure_thr = hi + EPS2;
  const float cand_lo = lo - EPS2;

  __shared__ uint32_t bitmap[HID / 32];
  __shared__ uint32_t s_nc, s_cs;
  bitmap[tid] = 0u;
  if (tid == 0) { s_nc = 0u; s_cs = 0u; }
  __syncthreads();

  uint32_t cs = 0;
#pragma unroll
  for (int i = 0; i < 4; ++i)
#pragma unroll
    for (int j = 0; j < 8; ++j) {
      const float v = vals[i * 8 + j];
      const int idx = tid * 8 + i * 4096 + j;
      if (v > sure_thr) {
        ++cs;
        atomicOr(&bitmap[idx >> 5], 1u << (idx & 31));
      } else if (v >= cand_lo) {
        uint32_t p = atomicAdd(&s_nc, 1u);
        if (p < CCAP) {
          cand_idx[(size_t)b * CCAP + p] = idx;
          cand_aval[(size_t)b * CCAP + p] = v;
        }
      }
    }
#pragma unroll
  for (int d = 1; d < 64; d <<= 1) cs += __shfl_xor(cs, d, 64);
  if (lane == 0) atomicAdd(&s_cs, cs);
  __syncthreads();

  if (tid == 0) {
    row_cnt[b] = (int)min(s_nc, (uint32_t)CCAP);
    row_need[b] = KACT - (int)s_cs;
  }

  uint32_t keepm = 0u;
  uint32_t c2 = 0;
#pragma unroll
  for (int i = 0; i < 4; ++i) {
    f32x4 o0, o1;
#pragma unroll
    for (int j = 0; j < 8; ++j) {
      const int idx = tid * 8 + i * 4096 + j;
      const float v = vals[i * 8 + j];
      const bool keep = (bitmap[idx >> 5] >> (idx & 31)) & 1u;
      const float ov = keep ? v : 0.0f;
      if (j < 4) o0[j] = ov; else o1[j - 4] = ov;
      if (keep) { keepm |= (1u << (i * 8 + j)); ++c2; }
    }
    *(f32x4*)(rowf + tid * 8 + i * 4096) = o0;
    *(f32x4*)(rowf + tid * 8 + i * 4096 + 4) = o1;
  }
  __shared__ uint32_t psum[8];
  uint32_t p = c2;
#pragma unroll
  for (int d = 1; d < 64; d <<= 1) {
    uint32_t o = __shfl_up(p, d, 64);
    if (lane >= d) p += o;
  }
  if (lane == 63) psum[wid] = p;
  __syncthreads();
  uint32_t off = 0;
  for (int w = 0; w < wid; ++w) off += psum[w];
  uint32_t posn = off + p - c2;
#pragma unroll
  for (int i = 0; i < 4; ++i)
#pragma unroll
    for (int j = 0; j < 8; ++j) {
      if ((keepm >> (i * 8 + j)) & 1u) {
        if (posn < KACT) {
          tk_idx[(size_t)b * KACT + posn] = tid * 8 + i * 4096 + j;
          tk_val[(size_t)b * KACT + posn] = vals[i * 8 + j];
        }
        ++posn;
      }
    }
}

// ---------------------------------------------------------------------------
// exact_patch: r17-identical (192 threads, panel-parallel np chains).
// ---------------------------------------------------------------------------
__global__ __launch_bounds__(192) void exact_patch(const float* __restrict__ x,
                                                   const float* __restrict__ Wenc,
                                                   const int* __restrict__ cand_idx,
                                                   const float* __restrict__ cand_aval,
                                                   const int* __restrict__ row_cnt,
                                                   const int* __restrict__ row_need,
                                                   float* __restrict__ enc,
                                                   int* __restrict__ tk_idx,
                                                   float* __restrict__ tk_val) {
  const int b = blockIdx.x;
  const int t = threadIdx.x;
  __shared__ float xs[IN_DIM];
  for (int i = t; i < IN_DIM / 4; i += 192)
    *(f32x4*)(xs + i * 4) = *(const f32x4*)(x + (size_t)b * IN_DIM + i * 4);

  const int cnt = row_cnt[b];
  const int need = row_need[b];
  __shared__ int eidx[CCAP];
  __shared__ float eaval[CCAP];
  __shared__ float spp[CCAP][3];
  __shared__ float evals[CCAP];
  for (int c = t; c < cnt; c += 192) {
    eidx[c] = cand_idx[(size_t)b * CCAP + c];
    eaval[c] = cand_aval[(size_t)b * CCAP + c];
  }
  __syncthreads();

  const int p = t >> 6;            // panel 0..2
  const int lane = t & 63;
  const int k0 = p * 384;
  const int k1 = (p == 2) ? 1024 : (k0 + 384);

  for (int c = lane; c < cnt; c += 64) {
    const float* w = Wenc + (size_t)eidx[c] * IN_DIM;
    float acc = 0.f;
    for (int k = k0; k < k1; k += 16) {
      const f32x4 w0 = *(const f32x4*)(w + k);
      const f32x4 w1 = *(const f32x4*)(w + k + 4);
      const f32x4 w2 = *(const f32x4*)(w + k + 8);
      const f32x4 w3 = *(const f32x4*)(w + k + 12);
#pragma unroll
      for (int j = 0; j < 4; ++j) acc = fmaf(xs[k + j], w0[j], acc);
#pragma unroll
      for (int j = 0; j < 4; ++j) acc = fmaf(xs[k + 4 + j], w1[j], acc);
#pragma unroll
      for (int j = 0; j < 4; ++j) acc = fmaf(xs[k + 8 + j], w2[j], acc);
#pragma unroll
      for (int j = 0; j < 4; ++j) acc = fmaf(xs[k + 12 + j], w3[j], acc);
    }
    spp[c][p] = acc;
  }
  __syncthreads();
  if (t < cnt) evals[t] = (spp[t][0] + spp[t][1]) + spp[t][2];
  __syncthreads();

  if (t < cnt && need > 0) {
    const float e = evals[t];
    const int myidx = eidx[t];
    int rank = 0;
    for (int c = 0; c < cnt; ++c)
      rank += (evals[c] > e) || (evals[c] == e && eidx[c] < myidx);
    if (rank < need) {
      const float v = eaval[t];
      enc[(size_t)b * HID + myidx] = v;
      const int slot = (KACT - need) + rank;
      tk_idx[(size_t)b * KACT + slot] = myidx;
      tk_val[(size_t)b * KACT + slot] = v;
    }
  }
}

// ---------------------------------------------------------------------------
// decoder_t: decoded[b,:] = sum_k val_k * WdT_b[idx_k,:] (bf16 weights).
// unroll 4 on the gather loop: 4 independent 8B row-gathers in flight
// (each iteration was a dependent ~200cy L2-latency load).
// ---------------------------------------------------------------------------
__global__ __launch_bounds__(256) void decoder_t(const int* __restrict__ tk_idx,
                                                 const float* __restrict__ tk_val,
                                                 const uint16_t* __restrict__ WdT_b,
                                                 float* __restrict__ out) {
  const int b = blockIdx.x;
  const int tid = threadIdx.x;
  __shared__ int sidx[KACT];
  __shared__ float sval[KACT];
  if (tid < KACT) {
    sidx[tid] = tk_idx[(size_t)b * KACT + tid];
    sval[tid] = tk_val[(size_t)b * KACT + tid];
  }
  __syncthreads();
  f32x4 acc = {0.f, 0.f, 0.f, 0.f};
#pragma unroll 4
  for (int k = 0; k < KACT; ++k) {
    const u16x4 w4 = *(const u16x4*)(WdT_b + (size_t)sidx[k] * IN_DIM + tid * 4);
    const float v = sval[k];
    acc[0] = fmaf(v, bf2f(w4[0]), acc[0]);
    acc[1] = fmaf(v, bf2f(w4[1]), acc[1]);
    acc[2] = fmaf(v, bf2f(w4[2]), acc[2]);
    acc[3] = fmaf(v, bf2f(w4[3]), acc[3]);
  }
  *(f32x4*)(out + (size_t)b * IN_DIM + tid * 4) = acc;
}

// ---------------------------------------------------------------------------
// W_dec [IN_DIM][HID] f32 -> W_decT [HID][IN_DIM] bf16, 64x64 tiles
// (4x work per block vs 32x32; fewer launch/index overheads).
// ---------------------------------------------------------------------------
__global__ __launch_bounds__(256) void transpose_wdec(const float* __restrict__ Wd,
                                                      uint16_t* __restrict__ WdT_b) {
  __shared__ float t[64][65];
  const int hb = blockIdx.x * 64;
  const int ib = blockIdx.y * 64;
  const int tx = threadIdx.x & 63;   // col within tile
  const int ty = threadIdx.x >> 6;   // 0..3
#pragma unroll
  for (int i = 0; i < 16; ++i) {
    const int r = ty + 4 * i;        // 0..63
    t[r][tx] = Wd[(size_t)(ib + r) * HID + hb + tx];
  }
  __syncthreads();
  const int tx2 = threadIdx.x & 31;  // col-pair 0..31 -> input rows 2*tx2,2*tx2+1
  const int ty2 = threadIdx.x >> 5;  // 0..7
#pragma unroll
  for (int i = 0; i < 8; ++i) {
    const int rr = ty2 + 8 * i;      // output row within tile 0..63
    uint32_t pk = (uint32_t)f2bf(t[2 * tx2][rr]) |
                  ((uint32_t)f2bf(t[2 * tx2 + 1][rr]) << 16);
    *(uint32_t*)(WdT_b + (size_t)(hb + rr) * IN_DIM + ib + 2 * tx2) = pk;
  }
}

// ---------------------------------------------------------------------------
// Fallback (r3-proven): fp32 vector GEMM + radix topk + gather decoder
// ---------------------------------------------------------------------------
__global__ __launch_bounds__(256) void enc_gemm(const float* __restrict__ A,
                                                const float* __restrict__ Bw,
                                                float* __restrict__ C) {
  __shared__ float As[16][132];
  __shared__ float Bs[16][132];
  const int tid = threadIdx.x;
  const int bm = blockIdx.y;
  const int bn = blockIdx.x;
  const int m0 = (tid >> 4) << 3;
  const int n0 = (tid & 15) << 3;
  float tot[8][8] = {};
  float acc[8][8] = {};
  const float* Ablk = A + (size_t)bm * 128 * IN_DIM;
  const float* Bblk = Bw + (size_t)bn * 128 * IN_DIM;
  for (int k0 = 0; k0 < IN_DIM; k0 += 16) {
#pragma unroll
    for (int l = 0; l < 2; ++l) {
      int li = tid + l * 256;
      int row = li >> 2;
      int c4 = (li & 3) << 2;
      float4 va = *reinterpret_cast<const float4*>(Ablk + (size_t)row * IN_DIM + k0 + c4);
      As[c4 + 0][row] = va.x; As[c4 + 1][row] = va.y;
      As[c4 + 2][row] = va.z; As[c4 + 3][row] = va.w;
      float4 vb = *reinterpret_cast<const float4*>(Bblk + (size_t)row * IN_DIM + k0 + c4);
      Bs[c4 + 0][row] = vb.x; Bs[c4 + 1][row] = vb.y;
      Bs[c4 + 2][row] = vb.z; Bs[c4 + 3][row] = vb.w;
    }
    __syncthreads();
#pragma unroll
    for (int kk = 0; kk < 16; ++kk) {
      float a[8], b[8];
#pragma unroll
      for (int i = 0; i < 8; ++i) a[i] = As[kk][m0 + i];
#pragma unroll
      for (int j = 0; j < 8; ++j) b[j] = Bs[kk][n0 + j];
#pragma unroll
      for (int i = 0; i < 8; ++i)
#pragma unroll
        for (int j = 0; j < 8; ++j) acc[i][j] = fmaf(a[i], b[j], acc[i][j]);
    }
    __syncthreads();
    const int kend = k0 + 16;
    if (kend == 384 || kend == 768 || kend == IN_DIM) {
#pragma unroll
      for (int i = 0; i < 8; ++i)
#pragma unroll
        for (int j = 0; j < 8; ++j) { tot[i][j] += acc[i][j]; acc[i][j] = 0.0f; }
    }
  }
  float* Cblk = C + (size_t)(bm * 128) * HID + bn * 128;
#pragma unroll
  for (int i = 0; i < 8; ++i) {
    float4 v0 = make_float4(tot[i][0], tot[i][1], tot[i][2], tot[i][3]);
    float4 v1 = make_float4(tot[i][4], tot[i][5], tot[i][6], tot[i][7]);
    *reinterpret_cast<float4*>(Cblk + (size_t)(m0 + i) * HID + n0) = v0;
    *reinterpret_cast<float4*>(Cblk + (size_t)(m0 + i) * HID + n0 + 4) = v1;
  }
}

__global__ __launch_bounds__(256) void topk_kernel(float* __restrict__ enc,
                                                   int* __restrict__ tk_idx,
                                                   float* __restrict__ tk_val) {
  const int b = blockIdx.x;
  const int tid = threadIdx.x;
  float* row = enc + (size_t)b * HID;
  uint32_t keys[64];
#pragma unroll
  for (int i = 0; i < 64; ++i) keys[i] = fmap(row[tid + (i << 8)]);
  __shared__ uint32_t hist[256];
  __shared__ uint32_t sfx[256];
  __shared__ uint32_t s_prefix, s_krem;
  __shared__ int eqidx[256];
  __shared__ uint32_t eqcnt;
  if (tid == 0) { s_prefix = 0u; s_krem = KACT; }
  for (int pass = 0; pass < 4; ++pass) {
    const int shift = 24 - pass * 8;
    hist[tid] = 0;
    __syncthreads();
    const uint32_t pm = pass ? (0xFFFFFFFFu << (shift + 8)) : 0u;
    const uint32_t prefix = s_prefix;
#pragma unroll
    for (int i = 0; i < 64; ++i)
      if ((keys[i] & pm) == prefix) atomicAdd(&hist[(keys[i] >> shift) & 255], 1u);
    __syncthreads();
    sfx[tid] = hist[tid];
    __syncthreads();
    for (int d = 1; d < 256; d <<= 1) {
      uint32_t add = (tid + d < 256) ? sfx[tid + d] : 0u;
      __syncthreads();
      sfx[tid] += add;
      __syncthreads();
    }
    const uint32_t krem = s_krem;
    __syncthreads();
    const uint32_t above = sfx[tid] - hist[tid];
    if (above < krem && sfx[tid] >= krem) {
      s_prefix = prefix | ((uint32_t)tid << shift);
      s_krem = krem - above;
    }
    __syncthreads();
  }
  const uint32_t T = s_prefix;
  const uint32_t take_eq = s_krem;
  if (tid == 0) eqcnt = 0;
  __syncthreads();
#pragma unroll
  for (int i = 0; i < 64; ++i)
    if (keys[i] == T) {
      uint32_t p = atomicAdd(&eqcnt, 1u);
      if (p < 256u) eqidx[p] = tid + (i << 8);
    }
  __syncthreads();
  if (tid == 0) {
    int n = (int)min(eqcnt, 256u);
    for (int a = 1; a < n; ++a) {
      int v = eqidx[a]; int c = a - 1;
      while (c >= 0 && eqidx[c] > v) { eqidx[c + 1] = eqidx[c]; --c; }
      eqidx[c + 1] = v;
    }
  }
  __syncthreads();
  uint64_t keepm = 0ull;
  uint32_t cnt = 0;
#pragma unroll
  for (int i = 0; i < 64; ++i) {
    const int idx = tid + (i << 8);
    const uint32_t u = keys[i];
    bool keep = (u > T);
    if (u == T) {
      for (uint32_t e = 0; e < take_eq; ++e)
        if (eqidx[e] == idx) { keep = true; break; }
    }
    if (keep) { keepm |= (1ull << i); ++cnt; }
  }
  sfx[tid] = cnt;
  __syncthreads();
  for (int d = 1; d < 256; d <<= 1) {
    uint32_t add = (tid >= d) ? sfx[tid - d] : 0u;
    __syncthreads();
    sfx[tid] += add;
    __syncthreads();
  }
  uint32_t pos = sfx[tid] - cnt;
#pragma unroll
  for (int i = 0; i < 64; ++i) {
    const int idx = tid + (i << 8);
    const uint32_t u = keys[i];
    const uint32_t sbits = (u & 0x80000000u) ? (u ^ 0x80000000u) : ~u;
    const float f = __uint_as_float(sbits);
    const bool keep = (keepm >> i) & 1ull;
    row[idx] = keep ? f : 0.0f;
    if (keep) {
      tk_idx[(size_t)b * KACT + pos] = idx;
      tk_val[(size_t)b * KACT + pos] = f;
      ++pos;
    }
  }
}

__global__ __launch_bounds__(256) void decoder_g(const int* __restrict__ tk_idx,
                                                 const float* __restrict__ tk_val,
                                                 const float* __restrict__ Wd,
                                                 float* __restrict__ out) {
  const int b = blockIdx.x;
  const int tid = threadIdx.x;
  __shared__ int sidx[KACT];
  __shared__ float sval[KACT];
  if (tid < KACT) {
    sidx[tid] = tk_idx[(size_t)b * KACT + tid];
    sval[tid] = tk_val[(size_t)b * KACT + tid];
  }
  __syncthreads();
  float acc[4] = {0.f, 0.f, 0.f, 0.f};
  for (int k = 0; k < KACT; ++k) {
    const int h = sidx[k];
    const float v = sval[k];
#pragma unroll
    for (int j = 0; j < 4; ++j)
      acc[j] = fmaf(v, Wd[(size_t)(tid + j * 256) * HID + h], acc[j]);
  }
#pragma unroll
  for (int j = 0; j < 4; ++j) out[(size_t)b * IN_DIM + tid + j * 256] = acc[j];
}

// ---------------------------------------------------------------------------
extern "C" void kernel_launch(void* const* d_in, const int* in_sizes, int n_in,
                              void* d_out, int out_size, void* d_ws, size_t ws_size,
                              hipStream_t stream) {
  const float* x = (const float*)d_in[0];
  const float* Wenc = (const float*)d_in[1];
  const float* Wdec = (const float*)d_in[2];
  float* out = (float*)d_out;
  float* decoded = out;
  float* sparse = out + (size_t)BATCH * IN_DIM;

  const size_t MB = 1024ull * 1024ull;
  char* ws = (char*)d_ws;
  int*   tk_idx    = (int*)(ws + 0 * MB);
  float* tk_val    = (float*)(ws + 1 * MB);
  int*   cand_idx  = (int*)(ws + 2 * MB);
  float* cand_aval = (float*)(ws + 4 * MB);
  int*   row_cnt   = (int*)(ws + 6 * MB);
  int*   row_need  = (int*)(ws + 6 * MB + 65536);
  uint16_t* A2     = (uint16_t*)(ws + 8 * MB);
  uint16_t* B2     = (uint16_t*)(ws + 16 * MB);
  uint16_t* WdT_b  = (uint16_t*)(ws + 48 * MB);

  const size_t need_new = 80 * MB;

  if (ws_size >= need_new) {
    convert_both<<<2048, 256, 0, stream>>>(x, Wenc, A2, B2);
    mfma_gemm<<<4096, 256, 0, stream>>>(A2, B2, (uint16_t*)sparse);
    transpose_wdec<<<dim3(HID / 64, IN_DIM / 64), 256, 0, stream>>>(Wdec, WdT_b);
    select_bin<<<BATCH, 512, 0, stream>>>(sparse, tk_idx, tk_val, cand_idx,
                                          cand_aval, row_cnt, row_need);
    exact_patch<<<BATCH, 192, 0, stream>>>(x, Wenc, cand_idx, cand_aval,
                                           row_cnt, row_need, sparse,
                                           tk_idx, tk_val);
    decoder_t<<<BATCH, 256, 0, stream>>>(tk_idx, tk_val, WdT_b, decoded);
  } else {
    enc_gemm<<<dim3(HID / 128, BATCH / 128), 256, 0, stream>>>(x, Wenc, sparse);
    topk_kernel<<<BATCH, 256, 0, stream>>>(sparse, tk_idx, tk_val);
    decoder_g<<<BATCH, 256, 0, stream>>>(tk_idx, tk_val, Wdec, decoded);
  }
}